// Round 6
// baseline (609.885 us; speedup 1.0000x reference)
//
#include <hip/hip_runtime.h>
#include <hip/hip_bf16.h>

// Transformer block: B=4 T=2048 C=384 H=6 HS=64.
// Reference softmax is over the QUERY axis -> w[t,s] = exp(S[t,s])/colsum[s],
// colsum[s] = sum_{t>=s} exp(S[t,s]).  Pipeline: colsum pass, then out = E @ (V/colsum).
//
// R6: split the causal s-loop across blockIdx.z chunks of 8 tiles (plain 3D grid,
// no mapping helpers — R3/R4's bug lived in new helper/path code). Attention
// accumulates fp32 atomically into d_out, then a cast kernel emits bf16 and the
// R2-proven bf16 proj GEMM consumes it. Critical path: 32 -> 8 iterations/wave.
// WS plan: R2-proven 28,901,376 B.

#define BB 4
#define TT 2048
#define CC 384
#define HH 6
#define HS 64
#define BT 8192
#define C4 1536
#define SCALE 0.05103103630798288f   // 384^-0.5

typedef __attribute__((ext_vector_type(8))) short short8;   // 8 x bf16
typedef __attribute__((ext_vector_type(4))) float f32x4;
typedef __hip_bfloat16 bf16_t;

__device__ inline short8 ld8(const bf16_t* p) { return *reinterpret_cast<const short8*>(p); }
#define MFMA(a, b, c) __builtin_amdgcn_mfma_f32_16x16x32_bf16(a, b, c, 0, 0, 0)

// ---------------- zero-init ----------------
__global__ __launch_bounds__(256) void zinit_kernel(float* __restrict__ p, int n4) {
    int i = blockIdx.x * 256 + threadIdx.x;
    if (i < n4) ((f32x4*)p)[i] = (f32x4){0.f, 0.f, 0.f, 0.f};
}

// ---------------- fp32 -> bf16 elementwise (4 per thread) ----------------
__global__ __launch_bounds__(256) void castbf_kernel(const float* __restrict__ src,
                                                     bf16_t* __restrict__ dst) {
    int i = (blockIdx.x * 256 + threadIdx.x) * 4;
    f32x4 v = *(const f32x4*)(src + i);
#pragma unroll
    for (int j = 0; j < 4; j++) dst[i + j] = __float2bfloat16(v[j]);
}

// ---------------- weight transpose + cast: dst[b][c][r] = src[b][r][c] ----------------
__global__ __launch_bounds__(256) void tcast_kernel(const float* __restrict__ src,
                                                    bf16_t* __restrict__ dst,
                                                    int R, int Cc, int total) {
    int idx = blockIdx.x * 256 + threadIdx.x;
    if (idx >= total) return;
    int rc = R * Cc;
    int b = idx / rc;
    int rem = idx - b * rc;
    int r = rem / Cc;
    int c = rem - r * Cc;
    dst[b * rc + c * R + r] = __float2bfloat16(src[idx]);
}

// ---------------- LayerNorm: one wave per row of 384 ----------------
__global__ __launch_bounds__(256) void ln_kernel(const float* __restrict__ x,
                                                 const float* __restrict__ g,
                                                 const float* __restrict__ be,
                                                 bf16_t* __restrict__ out) {
    int wave = threadIdx.x >> 6, lane = threadIdx.x & 63;
    int row = blockIdx.x * 4 + wave;
    const float* xr = x + (size_t)row * CC;
    float v[6];
    float s = 0.f;
#pragma unroll
    for (int i = 0; i < 6; i++) { v[i] = xr[lane + i * 64]; s += v[i]; }
#pragma unroll
    for (int off = 32; off > 0; off >>= 1) s += __shfl_xor(s, off, 64);
    float mean = s * (1.f / 384.f);
    float s2 = 0.f;
#pragma unroll
    for (int i = 0; i < 6; i++) { float d = v[i] - mean; s2 += d * d; }
#pragma unroll
    for (int off = 32; off > 0; off >>= 1) s2 += __shfl_xor(s2, off, 64);
    float rstd = rsqrtf(s2 * (1.f / 384.f) + 1e-5f);
    bf16_t* orow = out + (size_t)row * CC;
#pragma unroll
    for (int i = 0; i < 6; i++) {
        int c = lane + i * 64;
        orow[c] = __float2bfloat16((v[i] - mean) * rstd * g[c] + be[c]);
    }
}

// ---------------- 64x64 MFMA tile core. A: MxK row-major. Bt: NxK row-major (B transposed). ----------------
// A-frag: A[m=lane&15][k=quad*8+j]; B-frag: Bt[n=lane&15][k=quad*8+j]; D: row=quad*4+reg, col=lane&15.
__device__ inline void gemm_core(const bf16_t* __restrict__ A, const bf16_t* __restrict__ Bt,
                                 int m0, int n0, int lda, int ldb, int K, f32x4 acc[2][2]) {
    const int lane = threadIdx.x & 63;
    const int wave = threadIdx.x >> 6;
    const int wm = (wave >> 1) * 32, wn = (wave & 1) * 32;
    const int r16 = lane & 15, quad = lane >> 4;
    const bf16_t* Ap = A + (size_t)(m0 + wm + r16) * lda + quad * 8;
    const bf16_t* Bp = Bt + (size_t)(n0 + wn + r16) * ldb + quad * 8;
    for (int k = 0; k < K; k += 32) {
        short8 a0 = ld8(Ap + k);
        short8 a1 = ld8(Ap + (size_t)16 * lda + k);
        short8 b0 = ld8(Bp + k);
        short8 b1 = ld8(Bp + (size_t)16 * ldb + k);
        acc[0][0] = MFMA(a0, b0, acc[0][0]);
        acc[0][1] = MFMA(a0, b1, acc[0][1]);
        acc[1][0] = MFMA(a1, b0, acc[1][0]);
        acc[1][1] = MFMA(a1, b1, acc[1][1]);
    }
}

// ---------------- QKV projection: h(8192x384) @ per-head W(384x64) -> q,k bf16 + V^T bf16 ----------------
__global__ __launch_bounds__(256) void qkv_kernel(const bf16_t* __restrict__ hbf,
                                                  const bf16_t* __restrict__ wqt,
                                                  const bf16_t* __restrict__ wkt,
                                                  const bf16_t* __restrict__ wvt,
                                                  bf16_t* __restrict__ qbf,
                                                  bf16_t* __restrict__ kbf,
                                                  bf16_t* __restrict__ vt) {
    int mt = blockIdx.x, j = blockIdx.y;
    int mat = j / 6, head = j - mat * 6;
    const bf16_t* Bt = (mat == 0 ? wqt : (mat == 1 ? wkt : wvt)) + head * (HS * CC);
    f32x4 zero = {0.f, 0.f, 0.f, 0.f};
    f32x4 acc[2][2] = {{zero, zero}, {zero, zero}};
    gemm_core(hbf, Bt, mt * 64, 0, CC, CC, CC, acc);
    const int lane = threadIdx.x & 63, wave = threadIdx.x >> 6;
    const int wm = (wave >> 1) * 32, wn = (wave & 1) * 32;
    const int col = lane & 15, quad = lane >> 4;
#pragma unroll
    for (int mi = 0; mi < 2; mi++)
#pragma unroll
        for (int ni = 0; ni < 2; ni++)
#pragma unroll
            for (int reg = 0; reg < 4; reg++) {
                int m = mt * 64 + wm + mi * 16 + quad * 4 + reg;
                int d = wn + ni * 16 + col;
                int b = m >> 11, t = m & 2047;
                int bh = b * HH + head;
                float val = acc[mi][ni][reg];
                if (mat == 0)      qbf[(size_t)(bh * TT + t) * HS + d] = __float2bfloat16(val);
                else if (mat == 1) kbf[(size_t)(bh * TT + t) * HS + d] = __float2bfloat16(val);
                else               vt[(size_t)(bh * HS + d) * TT + t] = __float2bfloat16(val);
            }
}

// ---------------- colsum partial: block (stile, bh, z); z covers tt in [stile+8z, stile+8z+8) ----------------
__global__ __launch_bounds__(256) void colsum_kernel(const bf16_t* __restrict__ qbf,
                                                     const bf16_t* __restrict__ kbf,
                                                     float* __restrict__ colsum) {
    int stile = blockIdx.x, bh = blockIdx.y, z = blockIdx.z;
    if (stile + z * 8 > 31) return;         // chunk entirely past the end
    int s0 = stile * 64;
    const int lane = threadIdx.x & 63, wave = threadIdx.x >> 6;
    const int r16 = lane & 15, quad = lane >> 4;
    __shared__ float csum[64];
    if (threadIdx.x < 64) csum[threadIdx.x] = 0.f;
    __syncthreads();
    short8 bfr[4][2];
#pragma unroll
    for (int ns = 0; ns < 4; ns++)
#pragma unroll
        for (int kk = 0; kk < 2; kk++)
            bfr[ns][kk] = ld8(kbf + (size_t)(bh * TT + s0 + ns * 16 + r16) * HS + kk * 32 + quad * 8);
    float colacc[4] = {0.f, 0.f, 0.f, 0.f};
    for (int jj = wave; jj < 8; jj += 4) {
        int tt = stile + z * 8 + jj;
        if (tt > 31) break;
#pragma unroll
        for (int ms = 0; ms < 4; ms++) {
            const bf16_t* qp = qbf + (size_t)(bh * TT + tt * 64 + ms * 16 + r16) * HS + quad * 8;
            short8 a0 = ld8(qp);
            short8 a1 = ld8(qp + 32);
#pragma unroll
            for (int ns = 0; ns < 4; ns++) {
                f32x4 sacc = {0.f, 0.f, 0.f, 0.f};
                sacc = MFMA(a0, bfr[ns][0], sacc);
                sacc = MFMA(a1, bfr[ns][1], sacc);
#pragma unroll
                for (int reg = 0; reg < 4; reg++) {
                    int t = tt * 64 + ms * 16 + quad * 4 + reg;
                    int s = s0 + ns * 16 + r16;
                    if (s <= t) colacc[ns] += __expf(sacc[reg] * SCALE);
                }
            }
        }
    }
#pragma unroll
    for (int ns = 0; ns < 4; ns++) atomicAdd(&csum[ns * 16 + r16], colacc[ns]);
    __syncthreads();
    if (threadIdx.x < 64) atomicAdd(&colsum[bh * TT + s0 + threadIdx.x], csum[threadIdx.x]);
}

// ---------------- in-place: vst[bh][d][s] /= colsum[bh][s] ----------------
__global__ __launch_bounds__(256) void vscale_kernel(bf16_t* __restrict__ vst,
                                                     const float* __restrict__ colsum) {
    int idx = blockIdx.x * 256 + threadIdx.x;
    int s = idx & (TT - 1);
    int bh = idx >> 17;   // / (HS*TT)
    float v = __bfloat162float(vst[idx]);
    vst[idx] = __float2bfloat16(v / colsum[bh * TT + s]);
}

// ---------------- attention partial: block (ttile, bh, z); z covers st in [8z, min(8z+7, ttile)] ----------------
// Barrier-free core (R5-proven): El rows are wave-private; parity double-buffer
// breaks the cross-iteration WAR. fp32 atomicAdd epilogue into attnf.
__global__ __launch_bounds__(256) void attn_part_kernel(const bf16_t* __restrict__ qbf,
                                                        const bf16_t* __restrict__ kbf,
                                                        const bf16_t* __restrict__ vst,
                                                        float* __restrict__ attnf) {
    int ttile = blockIdx.x, bh = blockIdx.y, z = blockIdx.z;
    int sbeg = z * 8;
    if (sbeg > ttile) return;               // no work for this chunk
    int send = ttile + 1 < sbeg + 8 ? ttile + 1 : sbeg + 8;
    int t0 = ttile * 64;
    const int lane = threadIdx.x & 63, wave = threadIdx.x >> 6;
    const int r16 = lane & 15, quad = lane >> 4;
    __shared__ bf16_t El[2][64][72];   // +8 pad; [2] = parity double buffer
    f32x4 zero = {0.f, 0.f, 0.f, 0.f};
    f32x4 oacc[4] = {zero, zero, zero, zero};
    const bf16_t* qp = qbf + (size_t)(bh * TT + t0 + wave * 16 + r16) * HS + quad * 8;
    short8 qa0 = ld8(qp);
    short8 qa1 = ld8(qp + 32);
    for (int st = sbeg; st < send; st++) {
        int s0 = st * 64;
        bf16_t (*E)[72] = El[st & 1];
#pragma unroll
        for (int ns = 0; ns < 4; ns++) {
            const bf16_t* kp = kbf + (size_t)(bh * TT + s0 + ns * 16 + r16) * HS + quad * 8;
            f32x4 sacc = zero;
            sacc = MFMA(qa0, ld8(kp), sacc);
            sacc = MFMA(qa1, ld8(kp + 32), sacc);
#pragma unroll
            for (int reg = 0; reg < 4; reg++) {
                int t = t0 + wave * 16 + quad * 4 + reg;
                int s = s0 + ns * 16 + r16;
                float e = (s <= t) ? __expf(sacc[reg] * SCALE) : 0.f;
                E[wave * 16 + quad * 4 + reg][ns * 16 + r16] = __float2bfloat16(e);
            }
        }
        // no __syncthreads: rows [wave*16, wave*16+16) written+read by the same wave.
#pragma unroll
        for (int ks = 0; ks < 2; ks++) {
            short8 ea = ld8(&E[wave * 16 + r16][ks * 32 + quad * 8]);
#pragma unroll
            for (int ns = 0; ns < 4; ns++) {
                short8 vb = ld8(vst + (size_t)(bh * HS + ns * 16 + r16) * TT + s0 + ks * 32 + quad * 8);
                oacc[ns] = MFMA(ea, vb, oacc[ns]);
            }
        }
    }
    int b = bh / HH, head = bh - b * HH;
#pragma unroll
    for (int ns = 0; ns < 4; ns++)
#pragma unroll
        for (int reg = 0; reg < 4; reg++) {
            int t = t0 + wave * 16 + quad * 4 + reg;
            int d = ns * 16 + r16;
            atomicAdd(&attnf[(size_t)(b * TT + t) * CC + head * HS + d], oacc[ns][reg]);
        }
}

// ---------------- generic GEMM + epilogue. MODE 0: +bias+resid -> fp32. MODE 1: +bias, relu -> bf16 ----------------
template <int KDIM, int MODE>
__global__ __launch_bounds__(256) void gemm_kernel(const bf16_t* __restrict__ A,
                                                   const bf16_t* __restrict__ Bt,
                                                   const float* __restrict__ bias,
                                                   const float* __restrict__ resid,
                                                   void* __restrict__ out, int N) {
    int mt = blockIdx.x, nt = blockIdx.y;
    f32x4 zero = {0.f, 0.f, 0.f, 0.f};
    f32x4 acc[2][2] = {{zero, zero}, {zero, zero}};
    gemm_core(A, Bt, mt * 64, nt * 64, KDIM, KDIM, KDIM, acc);
    const int lane = threadIdx.x & 63, wave = threadIdx.x >> 6;
    const int wm = (wave >> 1) * 32, wn = (wave & 1) * 32;
    const int col = lane & 15, quad = lane >> 4;
#pragma unroll
    for (int mi = 0; mi < 2; mi++)
#pragma unroll
        for (int ni = 0; ni < 2; ni++)
#pragma unroll
            for (int reg = 0; reg < 4; reg++) {
                int m = mt * 64 + wm + mi * 16 + quad * 4 + reg;
                int n = nt * 64 + wn + ni * 16 + col;
                float val = acc[mi][ni][reg] + bias[n];
                if (MODE == 0)
                    ((float*)out)[(size_t)m * N + n] = val + resid[(size_t)m * N + n];
                else
                    ((bf16_t*)out)[(size_t)m * N + n] = __float2bfloat16(fmaxf(val, 0.f));
            }
}

extern "C" void kernel_launch(void* const* d_in, const int* in_sizes, int n_in,
                              void* d_out, int out_size, void* d_ws, size_t ws_size,
                              hipStream_t stream) {
    const float* x      = (const float*)d_in[0];
    const float* wq     = (const float*)d_in[1];
    const float* wk     = (const float*)d_in[2];
    const float* wv     = (const float*)d_in[3];
    const float* w_proj = (const float*)d_in[4];
    const float* b_proj = (const float*)d_in[5];
    const float* w1     = (const float*)d_in[6];
    const float* b1     = (const float*)d_in[7];
    const float* w2     = (const float*)d_in[8];
    const float* b2     = (const float*)d_in[9];
    const float* g1     = (const float*)d_in[10];
    const float* be1    = (const float*)d_in[11];
    const float* g2     = (const float*)d_in[12];
    const float* be2    = (const float*)d_in[13];
    float* out = (float*)d_out;

    // ---- R2-proven overlaid workspace plan (28,901,376 B) ----
    char* p = (char*)d_ws;
    auto alloc = [&](size_t bytes) {
        void* r = (void*)p;
        p += (bytes + 255) & ~(size_t)255;
        return r;
    };
    const size_t ACT  = (size_t)BT * CC * 2;      // 6291456 B, one bf16 activation
    bf16_t* wqt    = (bf16_t*)alloc(HH * HS * CC * 2);
    bf16_t* wkt    = (bf16_t*)alloc(HH * HS * CC * 2);
    bf16_t* wvt    = (bf16_t*)alloc(HH * HS * CC * 2);
    bf16_t* wpt    = (bf16_t*)alloc(CC * CC * 2);
    bf16_t* w1t    = (bf16_t*)alloc((size_t)C4 * CC * 2);
    bf16_t* w2t    = (bf16_t*)alloc((size_t)CC * C4 * 2);
    float*  colsum = (float*) alloc((size_t)24 * TT * 4);
    // slotA: h_bf (steps 2-3) -> attn_bf (post-cast -> proj) -> f1 chunk (mlp)
    char* slotA = (char*)alloc(ACT);
    // slotB: q_bf+k_bf (3-6) -> x1 fp32 (7-10)
    char* slotB = (char*)alloc(2 * ACT);
    // slotC: v_bf transposed (3-6) -> h2_bf (8-9)
    char* slotC = (char*)alloc(ACT);

    bf16_t* h_bf    = (bf16_t*)slotA;
    bf16_t* attn_bf = (bf16_t*)slotA;
    bf16_t* f1      = (bf16_t*)slotA;         // 2048 x 1536 bf16 chunk = 6291456 B
    bf16_t* q_bf    = (bf16_t*)slotB;
    bf16_t* k_bf    = (bf16_t*)(slotB + ACT);
    float*  x1      = (float*)slotB;          // 8192 x 384 fp32 = 12582912 B = 2*ACT
    bf16_t* v_bf    = (bf16_t*)slotC;         // [bh][d][t]
    bf16_t* h2_bf   = (bf16_t*)slotC;
    // fp32 attention accumulator lives in d_out (dead after the cast; mlp2 rewrites d_out)
    float* attn_f   = (float*)d_out;

    // 0. zero atomic accumulators (d_out is re-poisoned before every timed launch)
    zinit_kernel<<<48, 256, 0, stream>>>(colsum, 24*TT/4);
    zinit_kernel<<<3072, 256, 0, stream>>>(attn_f, BT*CC/4);
    // 1. weight transpose+cast
    tcast_kernel<<<(HH*CC*HS + 255)/256, 256, 0, stream>>>(wq, wqt, CC, HS, HH*CC*HS);
    tcast_kernel<<<(HH*CC*HS + 255)/256, 256, 0, stream>>>(wk, wkt, CC, HS, HH*CC*HS);
    tcast_kernel<<<(HH*CC*HS + 255)/256, 256, 0, stream>>>(wv, wvt, CC, HS, HH*CC*HS);
    tcast_kernel<<<(CC*CC + 255)/256, 256, 0, stream>>>(w_proj, wpt, CC, CC, CC*CC);
    tcast_kernel<<<(CC*C4 + 255)/256, 256, 0, stream>>>(w1, w1t, CC, C4, CC*C4);
    tcast_kernel<<<(C4*CC + 255)/256, 256, 0, stream>>>(w2, w2t, C4, CC, C4*CC);
    // 2. LN1
    ln_kernel<<<BT/4, 256, 0, stream>>>(x, g1, be1, h_bf);
    // 3. QKV
    qkv_kernel<<<dim3(BT/64, 18), 256, 0, stream>>>(h_bf, wqt, wkt, wvt, q_bf, k_bf, v_bf);
    // 4. column sums of exp(scores) — split over t-chunks, atomic
    colsum_kernel<<<dim3(32, 24, 4), 256, 0, stream>>>(q_bf, k_bf, colsum);
    // 5. V /= colsum (in place)
    vscale_kernel<<<(24*HS*TT)/256, 256, 0, stream>>>(v_bf, colsum);
    // 6. attention — split over s-chunks, fp32 atomic accumulate into d_out
    attn_part_kernel<<<dim3(32, 24, 4), 256, 0, stream>>>(q_bf, k_bf, v_bf, attn_f);
    // 6b. cast accumulator to bf16 (h dead; slotA free)
    castbf_kernel<<<3072, 256, 0, stream>>>(attn_f, attn_bf);
    // 7. proj + bias + residual -> x1 (q,k dead) — R2-proven bf16 path
    gemm_kernel<CC, 0><<<dim3(BT/64, CC/64), 256, 0, stream>>>(attn_bf, wpt, b_proj, x, x1, CC);
    // 8. LN2 -> h2 (v dead)
    ln_kernel<<<BT/4, 256, 0, stream>>>(x1, g2, be2, h2_bf);
    // 9+10. MLP in 4 row-chunks of 2048 (f1 overlays attn_bf, dead)
    for (int c = 0; c < 4; c++) {
        size_t m0 = (size_t)c * 2048;
        gemm_kernel<CC, 1><<<dim3(2048/64, C4/64), 256, 0, stream>>>(
            h2_bf + m0 * CC, w1t, b1, nullptr, f1, C4);
        gemm_kernel<C4, 0><<<dim3(2048/64, CC/64), 256, 0, stream>>>(
            f1, w2t, b2, x1 + m0 * CC, out + m0 * CC, CC);
    }
}

// Round 7
// 568.566 us; speedup vs baseline: 1.0727x; 1.0727x over previous
//
#include <hip/hip_runtime.h>
#include <hip/hip_bf16.h>

// Transformer block: B=4 T=2048 C=384 H=6 HS=64.
// Reference softmax is over the QUERY axis -> w[t,s] = exp(S[t,s])/colsum[s],
// colsum[s] = sum_{t>=s} exp(S[t,s]).  Pipeline: colsum pass, then out = E @ (V/colsum).
//
// R7 = R6 (proven) + ONE change: V^T row stride padded 2048 -> 2080 elements
// (4096B -> 4160B). R6 showed occupancy 18->32% with dur_us flat at 185 and all
// pipes <8%: the cap is the exact-4KB-stride V^T reads aliasing HBM channels /
// L2 sets (FETCH 48MB vs 18MB ideal; colsum, which skips V, is faster).
// colsum buffer overlays the dead wq/wk/wv cast region to pay for the pad:
// total ws = 28,803,072 B < proven 28,901,376 B.

#define BB 4
#define TT 2048
#define CC 384
#define HH 6
#define HS 64
#define BT 8192
#define C4 1536
#define VST 2080              // padded V^T leading dim (elements): 4160B rows
#define SCALE 0.05103103630798288f   // 384^-0.5

typedef __attribute__((ext_vector_type(8))) short short8;   // 8 x bf16
typedef __attribute__((ext_vector_type(4))) float f32x4;
typedef __hip_bfloat16 bf16_t;

__device__ inline short8 ld8(const bf16_t* p) { return *reinterpret_cast<const short8*>(p); }
#define MFMA(a, b, c) __builtin_amdgcn_mfma_f32_16x16x32_bf16(a, b, c, 0, 0, 0)

// ---------------- zero-init ----------------
__global__ __launch_bounds__(256) void zinit_kernel(float* __restrict__ p, int n4) {
    int i = blockIdx.x * 256 + threadIdx.x;
    if (i < n4) ((f32x4*)p)[i] = (f32x4){0.f, 0.f, 0.f, 0.f};
}

// ---------------- fp32 -> bf16 elementwise (4 per thread) ----------------
__global__ __launch_bounds__(256) void castbf_kernel(const float* __restrict__ src,
                                                     bf16_t* __restrict__ dst) {
    int i = (blockIdx.x * 256 + threadIdx.x) * 4;
    f32x4 v = *(const f32x4*)(src + i);
#pragma unroll
    for (int j = 0; j < 4; j++) dst[i + j] = __float2bfloat16(v[j]);
}

// ---------------- weight transpose + cast: dst[b][c][r] = src[b][r][c] ----------------
__global__ __launch_bounds__(256) void tcast_kernel(const float* __restrict__ src,
                                                    bf16_t* __restrict__ dst,
                                                    int R, int Cc, int total) {
    int idx = blockIdx.x * 256 + threadIdx.x;
    if (idx >= total) return;
    int rc = R * Cc;
    int b = idx / rc;
    int rem = idx - b * rc;
    int r = rem / Cc;
    int c = rem - r * Cc;
    dst[b * rc + c * R + r] = __float2bfloat16(src[idx]);
}

// ---------------- LayerNorm: one wave per row of 384 ----------------
__global__ __launch_bounds__(256) void ln_kernel(const float* __restrict__ x,
                                                 const float* __restrict__ g,
                                                 const float* __restrict__ be,
                                                 bf16_t* __restrict__ out) {
    int wave = threadIdx.x >> 6, lane = threadIdx.x & 63;
    int row = blockIdx.x * 4 + wave;
    const float* xr = x + (size_t)row * CC;
    float v[6];
    float s = 0.f;
#pragma unroll
    for (int i = 0; i < 6; i++) { v[i] = xr[lane + i * 64]; s += v[i]; }
#pragma unroll
    for (int off = 32; off > 0; off >>= 1) s += __shfl_xor(s, off, 64);
    float mean = s * (1.f / 384.f);
    float s2 = 0.f;
#pragma unroll
    for (int i = 0; i < 6; i++) { float d = v[i] - mean; s2 += d * d; }
#pragma unroll
    for (int off = 32; off > 0; off >>= 1) s2 += __shfl_xor(s2, off, 64);
    float rstd = rsqrtf(s2 * (1.f / 384.f) + 1e-5f);
    bf16_t* orow = out + (size_t)row * CC;
#pragma unroll
    for (int i = 0; i < 6; i++) {
        int c = lane + i * 64;
        orow[c] = __float2bfloat16((v[i] - mean) * rstd * g[c] + be[c]);
    }
}

// ---------------- 64x64 MFMA tile core. A: MxK row-major. Bt: NxK row-major (B transposed). ----------------
// A-frag: A[m=lane&15][k=quad*8+j]; B-frag: Bt[n=lane&15][k=quad*8+j]; D: row=quad*4+reg, col=lane&15.
__device__ inline void gemm_core(const bf16_t* __restrict__ A, const bf16_t* __restrict__ Bt,
                                 int m0, int n0, int lda, int ldb, int K, f32x4 acc[2][2]) {
    const int lane = threadIdx.x & 63;
    const int wave = threadIdx.x >> 6;
    const int wm = (wave >> 1) * 32, wn = (wave & 1) * 32;
    const int r16 = lane & 15, quad = lane >> 4;
    const bf16_t* Ap = A + (size_t)(m0 + wm + r16) * lda + quad * 8;
    const bf16_t* Bp = Bt + (size_t)(n0 + wn + r16) * ldb + quad * 8;
    for (int k = 0; k < K; k += 32) {
        short8 a0 = ld8(Ap + k);
        short8 a1 = ld8(Ap + (size_t)16 * lda + k);
        short8 b0 = ld8(Bp + k);
        short8 b1 = ld8(Bp + (size_t)16 * ldb + k);
        acc[0][0] = MFMA(a0, b0, acc[0][0]);
        acc[0][1] = MFMA(a0, b1, acc[0][1]);
        acc[1][0] = MFMA(a1, b0, acc[1][0]);
        acc[1][1] = MFMA(a1, b1, acc[1][1]);
    }
}

// ---------------- QKV projection: h(8192x384) @ per-head W(384x64) -> q,k bf16 + V^T bf16 (padded) ----------------
__global__ __launch_bounds__(256) void qkv_kernel(const bf16_t* __restrict__ hbf,
                                                  const bf16_t* __restrict__ wqt,
                                                  const bf16_t* __restrict__ wkt,
                                                  const bf16_t* __restrict__ wvt,
                                                  bf16_t* __restrict__ qbf,
                                                  bf16_t* __restrict__ kbf,
                                                  bf16_t* __restrict__ vt) {
    int mt = blockIdx.x, j = blockIdx.y;
    int mat = j / 6, head = j - mat * 6;
    const bf16_t* Bt = (mat == 0 ? wqt : (mat == 1 ? wkt : wvt)) + head * (HS * CC);
    f32x4 zero = {0.f, 0.f, 0.f, 0.f};
    f32x4 acc[2][2] = {{zero, zero}, {zero, zero}};
    gemm_core(hbf, Bt, mt * 64, 0, CC, CC, CC, acc);
    const int lane = threadIdx.x & 63, wave = threadIdx.x >> 6;
    const int wm = (wave >> 1) * 32, wn = (wave & 1) * 32;
    const int col = lane & 15, quad = lane >> 4;
#pragma unroll
    for (int mi = 0; mi < 2; mi++)
#pragma unroll
        for (int ni = 0; ni < 2; ni++)
#pragma unroll
            for (int reg = 0; reg < 4; reg++) {
                int m = mt * 64 + wm + mi * 16 + quad * 4 + reg;
                int d = wn + ni * 16 + col;
                int b = m >> 11, t = m & 2047;
                int bh = b * HH + head;
                float val = acc[mi][ni][reg];
                if (mat == 0)      qbf[(size_t)(bh * TT + t) * HS + d] = __float2bfloat16(val);
                else if (mat == 1) kbf[(size_t)(bh * TT + t) * HS + d] = __float2bfloat16(val);
                else               vt[(size_t)(bh * HS + d) * VST + t] = __float2bfloat16(val);
            }
}

// ---------------- colsum partial: block (stile, bh, z); z covers tt in [stile+8z, stile+8z+8) ----------------
__global__ __launch_bounds__(256) void colsum_kernel(const bf16_t* __restrict__ qbf,
                                                     const bf16_t* __restrict__ kbf,
                                                     float* __restrict__ colsum) {
    int stile = blockIdx.x, bh = blockIdx.y, z = blockIdx.z;
    if (stile + z * 8 > 31) return;         // chunk entirely past the end
    int s0 = stile * 64;
    const int lane = threadIdx.x & 63, wave = threadIdx.x >> 6;
    const int r16 = lane & 15, quad = lane >> 4;
    __shared__ float csum[64];
    if (threadIdx.x < 64) csum[threadIdx.x] = 0.f;
    __syncthreads();
    short8 bfr[4][2];
#pragma unroll
    for (int ns = 0; ns < 4; ns++)
#pragma unroll
        for (int kk = 0; kk < 2; kk++)
            bfr[ns][kk] = ld8(kbf + (size_t)(bh * TT + s0 + ns * 16 + r16) * HS + kk * 32 + quad * 8);
    float colacc[4] = {0.f, 0.f, 0.f, 0.f};
    for (int jj = wave; jj < 8; jj += 4) {
        int tt = stile + z * 8 + jj;
        if (tt > 31) break;
#pragma unroll
        for (int ms = 0; ms < 4; ms++) {
            const bf16_t* qp = qbf + (size_t)(bh * TT + tt * 64 + ms * 16 + r16) * HS + quad * 8;
            short8 a0 = ld8(qp);
            short8 a1 = ld8(qp + 32);
#pragma unroll
            for (int ns = 0; ns < 4; ns++) {
                f32x4 sacc = {0.f, 0.f, 0.f, 0.f};
                sacc = MFMA(a0, bfr[ns][0], sacc);
                sacc = MFMA(a1, bfr[ns][1], sacc);
#pragma unroll
                for (int reg = 0; reg < 4; reg++) {
                    int t = tt * 64 + ms * 16 + quad * 4 + reg;
                    int s = s0 + ns * 16 + r16;
                    if (s <= t) colacc[ns] += __expf(sacc[reg] * SCALE);
                }
            }
        }
    }
#pragma unroll
    for (int ns = 0; ns < 4; ns++) atomicAdd(&csum[ns * 16 + r16], colacc[ns]);
    __syncthreads();
    if (threadIdx.x < 64) atomicAdd(&colsum[bh * TT + s0 + threadIdx.x], csum[threadIdx.x]);
}

// ---------------- in-place: vst[bh][d][s] /= colsum[bh][s]  (padded rows) ----------------
__global__ __launch_bounds__(256) void vscale_kernel(bf16_t* __restrict__ vst,
                                                     const float* __restrict__ colsum) {
    int idx = blockIdx.x * 256 + threadIdx.x;   // over 24*64*2048 logical elements
    int s  = idx & (TT - 1);
    int d  = (idx >> 11) & 63;
    int bh = idx >> 17;
    bf16_t* p = vst + (size_t)(bh * HS + d) * VST + s;
    float v = __bfloat162float(*p);
    *p = __float2bfloat16(v / colsum[bh * TT + s]);
}

// ---------------- attention partial: block (ttile, bh, z); z covers st in [8z, min(8z+7, ttile)] ----------------
// Barrier-free core (R5-proven): El rows are wave-private; parity double-buffer
// breaks the cross-iteration WAR. fp32 atomicAdd epilogue into attnf.
__global__ __launch_bounds__(256) void attn_part_kernel(const bf16_t* __restrict__ qbf,
                                                        const bf16_t* __restrict__ kbf,
                                                        const bf16_t* __restrict__ vst,
                                                        float* __restrict__ attnf) {
    int ttile = blockIdx.x, bh = blockIdx.y, z = blockIdx.z;
    int sbeg = z * 8;
    if (sbeg > ttile) return;               // no work for this chunk
    int send = ttile + 1 < sbeg + 8 ? ttile + 1 : sbeg + 8;
    int t0 = ttile * 64;
    const int lane = threadIdx.x & 63, wave = threadIdx.x >> 6;
    const int r16 = lane & 15, quad = lane >> 4;
    __shared__ bf16_t El[2][64][72];   // +8 pad; [2] = parity double buffer
    f32x4 zero = {0.f, 0.f, 0.f, 0.f};
    f32x4 oacc[4] = {zero, zero, zero, zero};
    const bf16_t* qp = qbf + (size_t)(bh * TT + t0 + wave * 16 + r16) * HS + quad * 8;
    short8 qa0 = ld8(qp);
    short8 qa1 = ld8(qp + 32);
    for (int st = sbeg; st < send; st++) {
        int s0 = st * 64;
        bf16_t (*E)[72] = El[st & 1];
#pragma unroll
        for (int ns = 0; ns < 4; ns++) {
            const bf16_t* kp = kbf + (size_t)(bh * TT + s0 + ns * 16 + r16) * HS + quad * 8;
            f32x4 sacc = zero;
            sacc = MFMA(qa0, ld8(kp), sacc);
            sacc = MFMA(qa1, ld8(kp + 32), sacc);
#pragma unroll
            for (int reg = 0; reg < 4; reg++) {
                int t = t0 + wave * 16 + quad * 4 + reg;
                int s = s0 + ns * 16 + r16;
                float e = (s <= t) ? __expf(sacc[reg] * SCALE) : 0.f;
                E[wave * 16 + quad * 4 + reg][ns * 16 + r16] = __float2bfloat16(e);
            }
        }
        // no __syncthreads: rows [wave*16, wave*16+16) written+read by the same wave.
#pragma unroll
        for (int ks = 0; ks < 2; ks++) {
            short8 ea = ld8(&E[wave * 16 + r16][ks * 32 + quad * 8]);
#pragma unroll
            for (int ns = 0; ns < 4; ns++) {
                short8 vb = ld8(vst + (size_t)(bh * HS + ns * 16 + r16) * VST + s0 + ks * 32 + quad * 8);
                oacc[ns] = MFMA(ea, vb, oacc[ns]);
            }
        }
    }
    int b = bh / HH, head = bh - b * HH;
#pragma unroll
    for (int ns = 0; ns < 4; ns++)
#pragma unroll
        for (int reg = 0; reg < 4; reg++) {
            int t = t0 + wave * 16 + quad * 4 + reg;
            int d = ns * 16 + r16;
            atomicAdd(&attnf[(size_t)(b * TT + t) * CC + head * HS + d], oacc[ns][reg]);
        }
}

// ---------------- generic GEMM + epilogue. MODE 0: +bias+resid -> fp32. MODE 1: +bias, relu -> bf16 ----------------
template <int KDIM, int MODE>
__global__ __launch_bounds__(256) void gemm_kernel(const bf16_t* __restrict__ A,
                                                   const bf16_t* __restrict__ Bt,
                                                   const float* __restrict__ bias,
                                                   const float* __restrict__ resid,
                                                   void* __restrict__ out, int N) {
    int mt = blockIdx.x, nt = blockIdx.y;
    f32x4 zero = {0.f, 0.f, 0.f, 0.f};
    f32x4 acc[2][2] = {{zero, zero}, {zero, zero}};
    gemm_core(A, Bt, mt * 64, nt * 64, KDIM, KDIM, KDIM, acc);
    const int lane = threadIdx.x & 63, wave = threadIdx.x >> 6;
    const int wm = (wave >> 1) * 32, wn = (wave & 1) * 32;
    const int col = lane & 15, quad = lane >> 4;
#pragma unroll
    for (int mi = 0; mi < 2; mi++)
#pragma unroll
        for (int ni = 0; ni < 2; ni++)
#pragma unroll
            for (int reg = 0; reg < 4; reg++) {
                int m = mt * 64 + wm + mi * 16 + quad * 4 + reg;
                int n = nt * 64 + wn + ni * 16 + col;
                float val = acc[mi][ni][reg] + bias[n];
                if (MODE == 0)
                    ((float*)out)[(size_t)m * N + n] = val + resid[(size_t)m * N + n];
                else
                    ((bf16_t*)out)[(size_t)m * N + n] = __float2bfloat16(fmaxf(val, 0.f));
            }
}

extern "C" void kernel_launch(void* const* d_in, const int* in_sizes, int n_in,
                              void* d_out, int out_size, void* d_ws, size_t ws_size,
                              hipStream_t stream) {
    const float* x      = (const float*)d_in[0];
    const float* wq     = (const float*)d_in[1];
    const float* wk     = (const float*)d_in[2];
    const float* wv     = (const float*)d_in[3];
    const float* w_proj = (const float*)d_in[4];
    const float* b_proj = (const float*)d_in[5];
    const float* w1     = (const float*)d_in[6];
    const float* b1     = (const float*)d_in[7];
    const float* w2     = (const float*)d_in[8];
    const float* b2     = (const float*)d_in[9];
    const float* g1     = (const float*)d_in[10];
    const float* be1    = (const float*)d_in[11];
    const float* g2     = (const float*)d_in[12];
    const float* be2    = (const float*)d_in[13];
    float* out = (float*)d_out;

    // ---- overlaid workspace plan, total 28,803,072 B (< proven 28,901,376) ----
    char* p = (char*)d_ws;
    auto alloc = [&](size_t bytes) {
        void* r = (void*)p;
        p += (bytes + 255) & ~(size_t)255;
        return r;
    };
    const size_t ACT  = (size_t)BT * CC * 2;      // 6291456 B, one bf16 activation
    bf16_t* wqt    = (bf16_t*)alloc(HH * HS * CC * 2);
    bf16_t* wkt    = (bf16_t*)alloc(HH * HS * CC * 2);
    bf16_t* wvt    = (bf16_t*)alloc(HH * HS * CC * 2);
    bf16_t* wpt    = (bf16_t*)alloc(CC * CC * 2);
    bf16_t* w1t    = (bf16_t*)alloc((size_t)C4 * CC * 2);
    bf16_t* w2t    = (bf16_t*)alloc((size_t)CC * C4 * 2);
    // slotA: h_bf (steps 2-3) -> attn_bf (post-cast -> proj) -> f1 chunk (mlp)
    char* slotA = (char*)alloc(ACT);
    // slotB: q_bf+k_bf (3-6) -> x1 fp32 (7-10)
    char* slotB = (char*)alloc(2 * ACT);
    // slotC: padded v^T (3-6) -> h2_bf (8-9); 24*64*2080*2 = 6,389,760 B
    char* slotC = (char*)alloc((size_t)24 * HS * VST * 2);

    bf16_t* h_bf    = (bf16_t*)slotA;
    bf16_t* attn_bf = (bf16_t*)slotA;
    bf16_t* f1      = (bf16_t*)slotA;         // 2048 x 1536 bf16 chunk = 6291456 B
    bf16_t* q_bf    = (bf16_t*)slotB;
    bf16_t* k_bf    = (bf16_t*)(slotB + ACT);
    float*  x1      = (float*)slotB;          // 8192 x 384 fp32 = 12582912 B = 2*ACT
    bf16_t* v_bf    = (bf16_t*)slotC;         // [bh][d][VST]
    bf16_t* h2_bf   = (bf16_t*)slotC;
    // colsum overlays the wq/wk/wv cast region (dead after qkv): 24*2048*4 = 196,608 B
    float* colsum   = (float*)wqt;
    // fp32 attention accumulator lives in d_out (dead after the cast; mlp2 rewrites d_out)
    float* attn_f   = (float*)d_out;

    // 0. zero attn accumulator (d_out is re-poisoned before every timed launch)
    zinit_kernel<<<3072, 256, 0, stream>>>(attn_f, BT*CC/4);
    // 1. weight transpose+cast
    tcast_kernel<<<(HH*CC*HS + 255)/256, 256, 0, stream>>>(wq, wqt, CC, HS, HH*CC*HS);
    tcast_kernel<<<(HH*CC*HS + 255)/256, 256, 0, stream>>>(wk, wkt, CC, HS, HH*CC*HS);
    tcast_kernel<<<(HH*CC*HS + 255)/256, 256, 0, stream>>>(wv, wvt, CC, HS, HH*CC*HS);
    tcast_kernel<<<(CC*CC + 255)/256, 256, 0, stream>>>(w_proj, wpt, CC, CC, CC*CC);
    tcast_kernel<<<(CC*C4 + 255)/256, 256, 0, stream>>>(w1, w1t, CC, C4, CC*C4);
    tcast_kernel<<<(C4*CC + 255)/256, 256, 0, stream>>>(w2, w2t, C4, CC, C4*CC);
    // 2. LN1
    ln_kernel<<<BT/4, 256, 0, stream>>>(x, g1, be1, h_bf);
    // 3. QKV (V written with padded stride)
    qkv_kernel<<<dim3(BT/64, 18), 256, 0, stream>>>(h_bf, wqt, wkt, wvt, q_bf, k_bf, v_bf);
    // 4. zero colsum (wqt dead now), then column sums of exp(scores)
    zinit_kernel<<<48, 256, 0, stream>>>(colsum, 24*TT/4);
    colsum_kernel<<<dim3(32, 24, 4), 256, 0, stream>>>(q_bf, k_bf, colsum);
    // 5. V /= colsum (in place, padded rows)
    vscale_kernel<<<(24*HS*TT)/256, 256, 0, stream>>>(v_bf, colsum);
    // 6. attention — split over s-chunks, fp32 atomic accumulate into d_out
    attn_part_kernel<<<dim3(32, 24, 4), 256, 0, stream>>>(q_bf, k_bf, v_bf, attn_f);
    // 6b. cast accumulator to bf16 (slotA free)
    castbf_kernel<<<3072, 256, 0, stream>>>(attn_f, attn_bf);
    // 7. proj + bias + residual -> x1 (q,k dead)
    gemm_kernel<CC, 0><<<dim3(BT/64, CC/64), 256, 0, stream>>>(attn_bf, wpt, b_proj, x, x1, CC);
    // 8. LN2 -> h2 (v dead)
    ln_kernel<<<BT/4, 256, 0, stream>>>(x1, g2, be2, h2_bf);
    // 9+10. MLP in 4 row-chunks of 2048 (f1 overlays attn_bf, dead)
    for (int c = 0; c < 4; c++) {
        size_t m0 = (size_t)c * 2048;
        gemm_kernel<CC, 1><<<dim3(2048/64, C4/64), 256, 0, stream>>>(
            h2_bf + m0 * CC, w1t, b1, nullptr, f1, C4);
        gemm_kernel<C4, 0><<<dim3(2048/64, CC/64), 256, 0, stream>>>(
            f1, w2t, b2, x1 + m0 * CC, out + m0 * CC, CC);
    }
}

// Round 8
// 485.353 us; speedup vs baseline: 1.2566x; 1.1714x over previous
//
#include <hip/hip_runtime.h>
#include <hip/hip_bf16.h>

// Transformer block: B=4 T=2048 C=384 H=6 HS=64.
// Reference softmax is over the QUERY axis -> w[t,s] = exp(S[t,s])/colsum[s],
// colsum[s] = sum_{t>=s} exp(S[t,s]).  Pipeline: colsum pass, then out = E @ (V/colsum).
//
// R8 = R7 (proven) + ONE change: attn stages the K-tile and V-tile in LDS once
// per block per s-iteration (was: each of the 4 waves loaded the same 8KB tiles
// from global -> 811 MB vmem traffic ~= 5.6 TB/s at the L2/L3 level, the real
// cap; all execution pipes were <10%). 4x traffic cut. 2-barrier iteration
// (proven harmless in R2/R5). LDS 27.6KB/block -> 5 blocks/CU.

#define BB 4
#define TT 2048
#define CC 384
#define HH 6
#define HS 64
#define BT 8192
#define C4 1536
#define VST 2080              // padded V^T leading dim (elements): 4160B rows
#define SCALE 0.05103103630798288f   // 384^-0.5

typedef __attribute__((ext_vector_type(8))) short short8;   // 8 x bf16
typedef __attribute__((ext_vector_type(4))) float f32x4;
typedef __hip_bfloat16 bf16_t;

__device__ inline short8 ld8(const bf16_t* p) { return *reinterpret_cast<const short8*>(p); }
#define MFMA(a, b, c) __builtin_amdgcn_mfma_f32_16x16x32_bf16(a, b, c, 0, 0, 0)

// ---------------- zero-init ----------------
__global__ __launch_bounds__(256) void zinit_kernel(float* __restrict__ p, int n4) {
    int i = blockIdx.x * 256 + threadIdx.x;
    if (i < n4) ((f32x4*)p)[i] = (f32x4){0.f, 0.f, 0.f, 0.f};
}

// ---------------- fp32 -> bf16 elementwise (4 per thread) ----------------
__global__ __launch_bounds__(256) void castbf_kernel(const float* __restrict__ src,
                                                     bf16_t* __restrict__ dst) {
    int i = (blockIdx.x * 256 + threadIdx.x) * 4;
    f32x4 v = *(const f32x4*)(src + i);
#pragma unroll
    for (int j = 0; j < 4; j++) dst[i + j] = __float2bfloat16(v[j]);
}

// ---------------- weight transpose + cast: dst[b][c][r] = src[b][r][c] ----------------
__global__ __launch_bounds__(256) void tcast_kernel(const float* __restrict__ src,
                                                    bf16_t* __restrict__ dst,
                                                    int R, int Cc, int total) {
    int idx = blockIdx.x * 256 + threadIdx.x;
    if (idx >= total) return;
    int rc = R * Cc;
    int b = idx / rc;
    int rem = idx - b * rc;
    int r = rem / Cc;
    int c = rem - r * Cc;
    dst[b * rc + c * R + r] = __float2bfloat16(src[idx]);
}

// ---------------- LayerNorm: one wave per row of 384 ----------------
__global__ __launch_bounds__(256) void ln_kernel(const float* __restrict__ x,
                                                 const float* __restrict__ g,
                                                 const float* __restrict__ be,
                                                 bf16_t* __restrict__ out) {
    int wave = threadIdx.x >> 6, lane = threadIdx.x & 63;
    int row = blockIdx.x * 4 + wave;
    const float* xr = x + (size_t)row * CC;
    float v[6];
    float s = 0.f;
#pragma unroll
    for (int i = 0; i < 6; i++) { v[i] = xr[lane + i * 64]; s += v[i]; }
#pragma unroll
    for (int off = 32; off > 0; off >>= 1) s += __shfl_xor(s, off, 64);
    float mean = s * (1.f / 384.f);
    float s2 = 0.f;
#pragma unroll
    for (int i = 0; i < 6; i++) { float d = v[i] - mean; s2 += d * d; }
#pragma unroll
    for (int off = 32; off > 0; off >>= 1) s2 += __shfl_xor(s2, off, 64);
    float rstd = rsqrtf(s2 * (1.f / 384.f) + 1e-5f);
    bf16_t* orow = out + (size_t)row * CC;
#pragma unroll
    for (int i = 0; i < 6; i++) {
        int c = lane + i * 64;
        orow[c] = __float2bfloat16((v[i] - mean) * rstd * g[c] + be[c]);
    }
}

// ---------------- 64x64 MFMA tile core. A: MxK row-major. Bt: NxK row-major (B transposed). ----------------
// A-frag: A[m=lane&15][k=quad*8+j]; B-frag: Bt[n=lane&15][k=quad*8+j]; D: row=quad*4+reg, col=lane&15.
__device__ inline void gemm_core(const bf16_t* __restrict__ A, const bf16_t* __restrict__ Bt,
                                 int m0, int n0, int lda, int ldb, int K, f32x4 acc[2][2]) {
    const int lane = threadIdx.x & 63;
    const int wave = threadIdx.x >> 6;
    const int wm = (wave >> 1) * 32, wn = (wave & 1) * 32;
    const int r16 = lane & 15, quad = lane >> 4;
    const bf16_t* Ap = A + (size_t)(m0 + wm + r16) * lda + quad * 8;
    const bf16_t* Bp = Bt + (size_t)(n0 + wn + r16) * ldb + quad * 8;
    for (int k = 0; k < K; k += 32) {
        short8 a0 = ld8(Ap + k);
        short8 a1 = ld8(Ap + (size_t)16 * lda + k);
        short8 b0 = ld8(Bp + k);
        short8 b1 = ld8(Bp + (size_t)16 * ldb + k);
        acc[0][0] = MFMA(a0, b0, acc[0][0]);
        acc[0][1] = MFMA(a0, b1, acc[0][1]);
        acc[1][0] = MFMA(a1, b0, acc[1][0]);
        acc[1][1] = MFMA(a1, b1, acc[1][1]);
    }
}

// ---------------- QKV projection: h(8192x384) @ per-head W(384x64) -> q,k bf16 + V^T bf16 (padded) ----------------
__global__ __launch_bounds__(256) void qkv_kernel(const bf16_t* __restrict__ hbf,
                                                  const bf16_t* __restrict__ wqt,
                                                  const bf16_t* __restrict__ wkt,
                                                  const bf16_t* __restrict__ wvt,
                                                  bf16_t* __restrict__ qbf,
                                                  bf16_t* __restrict__ kbf,
                                                  bf16_t* __restrict__ vt) {
    int mt = blockIdx.x, j = blockIdx.y;
    int mat = j / 6, head = j - mat * 6;
    const bf16_t* Bt = (mat == 0 ? wqt : (mat == 1 ? wkt : wvt)) + head * (HS * CC);
    f32x4 zero = {0.f, 0.f, 0.f, 0.f};
    f32x4 acc[2][2] = {{zero, zero}, {zero, zero}};
    gemm_core(hbf, Bt, mt * 64, 0, CC, CC, CC, acc);
    const int lane = threadIdx.x & 63, wave = threadIdx.x >> 6;
    const int wm = (wave >> 1) * 32, wn = (wave & 1) * 32;
    const int col = lane & 15, quad = lane >> 4;
#pragma unroll
    for (int mi = 0; mi < 2; mi++)
#pragma unroll
        for (int ni = 0; ni < 2; ni++)
#pragma unroll
            for (int reg = 0; reg < 4; reg++) {
                int m = mt * 64 + wm + mi * 16 + quad * 4 + reg;
                int d = wn + ni * 16 + col;
                int b = m >> 11, t = m & 2047;
                int bh = b * HH + head;
                float val = acc[mi][ni][reg];
                if (mat == 0)      qbf[(size_t)(bh * TT + t) * HS + d] = __float2bfloat16(val);
                else if (mat == 1) kbf[(size_t)(bh * TT + t) * HS + d] = __float2bfloat16(val);
                else               vt[(size_t)(bh * HS + d) * VST + t] = __float2bfloat16(val);
            }
}

// ---------------- colsum partial: block (stile, bh, z); z covers tt in [stile+8z, stile+8z+8) ----------------
__global__ __launch_bounds__(256) void colsum_kernel(const bf16_t* __restrict__ qbf,
                                                     const bf16_t* __restrict__ kbf,
                                                     float* __restrict__ colsum) {
    int stile = blockIdx.x, bh = blockIdx.y, z = blockIdx.z;
    if (stile + z * 8 > 31) return;         // chunk entirely past the end
    int s0 = stile * 64;
    const int lane = threadIdx.x & 63, wave = threadIdx.x >> 6;
    const int r16 = lane & 15, quad = lane >> 4;
    __shared__ float csum[64];
    if (threadIdx.x < 64) csum[threadIdx.x] = 0.f;
    __syncthreads();
    short8 bfr[4][2];
#pragma unroll
    for (int ns = 0; ns < 4; ns++)
#pragma unroll
        for (int kk = 0; kk < 2; kk++)
            bfr[ns][kk] = ld8(kbf + (size_t)(bh * TT + s0 + ns * 16 + r16) * HS + kk * 32 + quad * 8);
    float colacc[4] = {0.f, 0.f, 0.f, 0.f};
    for (int jj = wave; jj < 8; jj += 4) {
        int tt = stile + z * 8 + jj;
        if (tt > 31) break;
#pragma unroll
        for (int ms = 0; ms < 4; ms++) {
            const bf16_t* qp = qbf + (size_t)(bh * TT + tt * 64 + ms * 16 + r16) * HS + quad * 8;
            short8 a0 = ld8(qp);
            short8 a1 = ld8(qp + 32);
#pragma unroll
            for (int ns = 0; ns < 4; ns++) {
                f32x4 sacc = {0.f, 0.f, 0.f, 0.f};
                sacc = MFMA(a0, bfr[ns][0], sacc);
                sacc = MFMA(a1, bfr[ns][1], sacc);
#pragma unroll
                for (int reg = 0; reg < 4; reg++) {
                    int t = tt * 64 + ms * 16 + quad * 4 + reg;
                    int s = s0 + ns * 16 + r16;
                    if (s <= t) colacc[ns] += __expf(sacc[reg] * SCALE);
                }
            }
        }
    }
#pragma unroll
    for (int ns = 0; ns < 4; ns++) atomicAdd(&csum[ns * 16 + r16], colacc[ns]);
    __syncthreads();
    if (threadIdx.x < 64) atomicAdd(&colsum[bh * TT + s0 + threadIdx.x], csum[threadIdx.x]);
}

// ---------------- in-place: vst[bh][d][s] /= colsum[bh][s]  (padded rows) ----------------
__global__ __launch_bounds__(256) void vscale_kernel(bf16_t* __restrict__ vst,
                                                     const float* __restrict__ colsum) {
    int idx = blockIdx.x * 256 + threadIdx.x;   // over 24*64*2048 logical elements
    int s  = idx & (TT - 1);
    int d  = (idx >> 11) & 63;
    int bh = idx >> 17;
    bf16_t* p = vst + (size_t)(bh * HS + d) * VST + s;
    float v = __bfloat162float(*p);
    *p = __float2bfloat16(v / colsum[bh * TT + s]);
}

// ---------------- attention partial: block (ttile, bh, z); z covers st in [8z, min(8z+7, ttile)] ----------------
// R8: K-tile and V-tile cooperatively staged in LDS once per s-iteration (4x
// vmem traffic cut). 2-barrier iteration. El is wave-private (no barrier dep).
__global__ __launch_bounds__(256) void attn_part_kernel(const bf16_t* __restrict__ qbf,
                                                        const bf16_t* __restrict__ kbf,
                                                        const bf16_t* __restrict__ vst,
                                                        float* __restrict__ attnf) {
    int ttile = blockIdx.x, bh = blockIdx.y, z = blockIdx.z;
    int sbeg = z * 8;
    if (sbeg > ttile) return;               // no work for this chunk
    int send = ttile + 1 < sbeg + 8 ? ttile + 1 : sbeg + 8;
    int t0 = ttile * 64;
    const int lane = threadIdx.x & 63, wave = threadIdx.x >> 6;
    const int r16 = lane & 15, quad = lane >> 4;
    __shared__ bf16_t Ksh[64][72];     // K[s-off][d], +8 pad
    __shared__ bf16_t Vsh[64][72];     // V^T[d][s-off], +8 pad
    __shared__ bf16_t El[64][72];      // E[t-off][s-off], wave-private rows
    const int srow = threadIdx.x >> 2;          // staging row (64 rows x 4 threads)
    const int scol = (threadIdx.x & 3) << 4;    // staging col base (16 elems/thread pair)
    f32x4 zero = {0.f, 0.f, 0.f, 0.f};
    f32x4 oacc[4] = {zero, zero, zero, zero};
    const bf16_t* qp = qbf + (size_t)(bh * TT + t0 + wave * 16 + r16) * HS + quad * 8;
    short8 qa0 = ld8(qp);
    short8 qa1 = ld8(qp + 32);
    for (int st = sbeg; st < send; st++) {
        int s0 = st * 64;
        // ---- cooperative staging: 256 threads x 32B each per tile ----
        {
            const bf16_t* kp = kbf + (size_t)(bh * TT + s0 + srow) * HS + scol;
            short8 k0 = ld8(kp);
            short8 k1 = ld8(kp + 8);
            const bf16_t* vp = vst + (size_t)(bh * HS + srow) * VST + s0 + scol;
            short8 v0 = ld8(vp);
            short8 v1 = ld8(vp + 8);
            *(short8*)&Ksh[srow][scol]     = k0;
            *(short8*)&Ksh[srow][scol + 8] = k1;
            *(short8*)&Vsh[srow][scol]     = v0;
            *(short8*)&Vsh[srow][scol + 8] = v1;
        }
        __syncthreads();
        // ---- QK^T -> exp -> El (wave-private rows) ----
#pragma unroll
        for (int ns = 0; ns < 4; ns++) {
            f32x4 sacc = zero;
            sacc = MFMA(qa0, *(const short8*)&Ksh[ns * 16 + r16][quad * 8], sacc);
            sacc = MFMA(qa1, *(const short8*)&Ksh[ns * 16 + r16][32 + quad * 8], sacc);
#pragma unroll
            for (int reg = 0; reg < 4; reg++) {
                int t = t0 + wave * 16 + quad * 4 + reg;
                int s = s0 + ns * 16 + r16;
                float e = (s <= t) ? __expf(sacc[reg] * SCALE) : 0.f;
                El[wave * 16 + quad * 4 + reg][ns * 16 + r16] = __float2bfloat16(e);
            }
        }
        // ---- E @ Vs from LDS ----
#pragma unroll
        for (int ks = 0; ks < 2; ks++) {
            short8 ea = ld8(&El[wave * 16 + r16][ks * 32 + quad * 8]);
#pragma unroll
            for (int ns = 0; ns < 4; ns++) {
                short8 vb = *(const short8*)&Vsh[ns * 16 + r16][ks * 32 + quad * 8];
                oacc[ns] = MFMA(ea, vb, oacc[ns]);
            }
        }
        __syncthreads();   // protect Ksh/Vsh before next staging
    }
    int b = bh / HH, head = bh - b * HH;
#pragma unroll
    for (int ns = 0; ns < 4; ns++)
#pragma unroll
        for (int reg = 0; reg < 4; reg++) {
            int t = t0 + wave * 16 + quad * 4 + reg;
            int d = ns * 16 + r16;
            atomicAdd(&attnf[(size_t)(b * TT + t) * CC + head * HS + d], oacc[ns][reg]);
        }
}

// ---------------- generic GEMM + epilogue. MODE 0: +bias+resid -> fp32. MODE 1: +bias, relu -> bf16 ----------------
template <int KDIM, int MODE>
__global__ __launch_bounds__(256) void gemm_kernel(const bf16_t* __restrict__ A,
                                                   const bf16_t* __restrict__ Bt,
                                                   const float* __restrict__ bias,
                                                   const float* __restrict__ resid,
                                                   void* __restrict__ out, int N) {
    int mt = blockIdx.x, nt = blockIdx.y;
    f32x4 zero = {0.f, 0.f, 0.f, 0.f};
    f32x4 acc[2][2] = {{zero, zero}, {zero, zero}};
    gemm_core(A, Bt, mt * 64, nt * 64, KDIM, KDIM, KDIM, acc);
    const int lane = threadIdx.x & 63, wave = threadIdx.x >> 6;
    const int wm = (wave >> 1) * 32, wn = (wave & 1) * 32;
    const int col = lane & 15, quad = lane >> 4;
#pragma unroll
    for (int mi = 0; mi < 2; mi++)
#pragma unroll
        for (int ni = 0; ni < 2; ni++)
#pragma unroll
            for (int reg = 0; reg < 4; reg++) {
                int m = mt * 64 + wm + mi * 16 + quad * 4 + reg;
                int n = nt * 64 + wn + ni * 16 + col;
                float val = acc[mi][ni][reg] + bias[n];
                if (MODE == 0)
                    ((float*)out)[(size_t)m * N + n] = val + resid[(size_t)m * N + n];
                else
                    ((bf16_t*)out)[(size_t)m * N + n] = __float2bfloat16(fmaxf(val, 0.f));
            }
}

extern "C" void kernel_launch(void* const* d_in, const int* in_sizes, int n_in,
                              void* d_out, int out_size, void* d_ws, size_t ws_size,
                              hipStream_t stream) {
    const float* x      = (const float*)d_in[0];
    const float* wq     = (const float*)d_in[1];
    const float* wk     = (const float*)d_in[2];
    const float* wv     = (const float*)d_in[3];
    const float* w_proj = (const float*)d_in[4];
    const float* b_proj = (const float*)d_in[5];
    const float* w1     = (const float*)d_in[6];
    const float* b1     = (const float*)d_in[7];
    const float* w2     = (const float*)d_in[8];
    const float* b2     = (const float*)d_in[9];
    const float* g1     = (const float*)d_in[10];
    const float* be1    = (const float*)d_in[11];
    const float* g2     = (const float*)d_in[12];
    const float* be2    = (const float*)d_in[13];
    float* out = (float*)d_out;

    // ---- overlaid workspace plan, total 28,803,072 B (< proven 28,901,376) ----
    char* p = (char*)d_ws;
    auto alloc = [&](size_t bytes) {
        void* r = (void*)p;
        p += (bytes + 255) & ~(size_t)255;
        return r;
    };
    const size_t ACT  = (size_t)BT * CC * 2;      // 6291456 B, one bf16 activation
    bf16_t* wqt    = (bf16_t*)alloc(HH * HS * CC * 2);
    bf16_t* wkt    = (bf16_t*)alloc(HH * HS * CC * 2);
    bf16_t* wvt    = (bf16_t*)alloc(HH * HS * CC * 2);
    bf16_t* wpt    = (bf16_t*)alloc(CC * CC * 2);
    bf16_t* w1t    = (bf16_t*)alloc((size_t)C4 * CC * 2);
    bf16_t* w2t    = (bf16_t*)alloc((size_t)CC * C4 * 2);
    // slotA: h_bf (steps 2-3) -> attn_bf (post-cast -> proj) -> f1 chunk (mlp)
    char* slotA = (char*)alloc(ACT);
    // slotB: q_bf+k_bf (3-6) -> x1 fp32 (7-10)
    char* slotB = (char*)alloc(2 * ACT);
    // slotC: padded v^T (3-6) -> h2_bf (8-9); 24*64*2080*2 = 6,389,760 B
    char* slotC = (char*)alloc((size_t)24 * HS * VST * 2);

    bf16_t* h_bf    = (bf16_t*)slotA;
    bf16_t* attn_bf = (bf16_t*)slotA;
    bf16_t* f1      = (bf16_t*)slotA;         // 2048 x 1536 bf16 chunk = 6291456 B
    bf16_t* q_bf    = (bf16_t*)slotB;
    bf16_t* k_bf    = (bf16_t*)(slotB + ACT);
    float*  x1      = (float*)slotB;          // 8192 x 384 fp32 = 12582912 B = 2*ACT
    bf16_t* v_bf    = (bf16_t*)slotC;         // [bh][d][VST]
    bf16_t* h2_bf   = (bf16_t*)slotC;
    // colsum overlays the wq/wk/wv cast region (dead after qkv): 24*2048*4 = 196,608 B
    float* colsum   = (float*)wqt;
    // fp32 attention accumulator lives in d_out (dead after the cast; mlp2 rewrites d_out)
    float* attn_f   = (float*)d_out;

    // 0. zero attn accumulator (d_out is re-poisoned before every timed launch)
    zinit_kernel<<<3072, 256, 0, stream>>>(attn_f, BT*CC/4);
    // 1. weight transpose+cast
    tcast_kernel<<<(HH*CC*HS + 255)/256, 256, 0, stream>>>(wq, wqt, CC, HS, HH*CC*HS);
    tcast_kernel<<<(HH*CC*HS + 255)/256, 256, 0, stream>>>(wk, wkt, CC, HS, HH*CC*HS);
    tcast_kernel<<<(HH*CC*HS + 255)/256, 256, 0, stream>>>(wv, wvt, CC, HS, HH*CC*HS);
    tcast_kernel<<<(CC*CC + 255)/256, 256, 0, stream>>>(w_proj, wpt, CC, CC, CC*CC);
    tcast_kernel<<<(CC*C4 + 255)/256, 256, 0, stream>>>(w1, w1t, CC, C4, CC*C4);
    tcast_kernel<<<(C4*CC + 255)/256, 256, 0, stream>>>(w2, w2t, C4, CC, C4*CC);
    // 2. LN1
    ln_kernel<<<BT/4, 256, 0, stream>>>(x, g1, be1, h_bf);
    // 3. QKV (V written with padded stride)
    qkv_kernel<<<dim3(BT/64, 18), 256, 0, stream>>>(h_bf, wqt, wkt, wvt, q_bf, k_bf, v_bf);
    // 4. zero colsum (wqt dead now), then column sums of exp(scores)
    zinit_kernel<<<48, 256, 0, stream>>>(colsum, 24*TT/4);
    colsum_kernel<<<dim3(32, 24, 4), 256, 0, stream>>>(q_bf, k_bf, colsum);
    // 5. V /= colsum (in place, padded rows)
    vscale_kernel<<<(24*HS*TT)/256, 256, 0, stream>>>(v_bf, colsum);
    // 6. attention — split over s-chunks, LDS-staged tiles, fp32 atomic accumulate
    attn_part_kernel<<<dim3(32, 24, 4), 256, 0, stream>>>(q_bf, k_bf, v_bf, attn_f);
    // 6b. cast accumulator to bf16 (slotA free)
    castbf_kernel<<<3072, 256, 0, stream>>>(attn_f, attn_bf);
    // 7. proj + bias + residual -> x1 (q,k dead)
    gemm_kernel<CC, 0><<<dim3(BT/64, CC/64), 256, 0, stream>>>(attn_bf, wpt, b_proj, x, x1, CC);
    // 8. LN2 -> h2 (v dead)
    ln_kernel<<<BT/4, 256, 0, stream>>>(x1, g2, be2, h2_bf);
    // 9+10. MLP in 4 row-chunks of 2048 (f1 overlays attn_bf, dead)
    for (int c = 0; c < 4; c++) {
        size_t m0 = (size_t)c * 2048;
        gemm_kernel<CC, 1><<<dim3(2048/64, C4/64), 256, 0, stream>>>(
            h2_bf + m0 * CC, w1t, b1, nullptr, f1, C4);
        gemm_kernel<C4, 0><<<dim3(2048/64, CC/64), 256, 0, stream>>>(
            f1, w2t, b2, x1 + m0 * CC, out + m0 * CC, CC);
    }
}

// Round 9
// 369.689 us; speedup vs baseline: 1.6497x; 1.3129x over previous
//
#include <hip/hip_runtime.h>
#include <hip/hip_bf16.h>

// Transformer block: B=4 T=2048 C=384 H=6 HS=64.
// Reference softmax is over the QUERY axis -> w[t,s] = exp(S[t,s])/colsum[s],
// colsum[s] = sum_{t>=s} exp(S[t,s]).  Pipeline: colsum pass, then out = E @ (V/colsum).
//
// R9 = R8 (attn/colsum proven, kept byte-identical) + GEMM upgrade:
//  - gemm128: 128x128 tile, 4 waves, LDS-staged A/B (pad-40 rows: 2-way bank
//    aliasing only), same verified fragment lane math as the 64^2 core.
//  - QKV fused into ONE gemm128 over the contiguous wq^T|wk^T|wv^T wall (N=1152).
//  - x1 residual stored bf16 (error ~0.02 << 0.12 budget) -> MLP in 2 chunks of
//    4096 rows. LN templated for fp32/bf16 input.
//  - tcast: coalesced writes, strided (L2-absorbed) reads.
// WS total 28,803,072 B (== proven R7/R8 footprint).

#define BB 4
#define TT 2048
#define CC 384
#define HH 6
#define HS 64
#define BT 8192
#define C4 1536
#define VST 2080              // padded V^T leading dim (elements): 4160B rows
#define SCALE 0.05103103630798288f   // 384^-0.5

typedef __attribute__((ext_vector_type(8))) short short8;   // 8 x bf16
typedef __attribute__((ext_vector_type(4))) float f32x4;
typedef __hip_bfloat16 bf16_t;

__device__ inline short8 ld8(const bf16_t* p) { return *reinterpret_cast<const short8*>(p); }
__device__ inline float tof(float v) { return v; }
__device__ inline float tof(bf16_t v) { return __bfloat162float(v); }
#define MFMA(a, b, c) __builtin_amdgcn_mfma_f32_16x16x32_bf16(a, b, c, 0, 0, 0)

// ---------------- zero-init ----------------
__global__ __launch_bounds__(256) void zinit_kernel(float* __restrict__ p, int n4) {
    int i = blockIdx.x * 256 + threadIdx.x;
    if (i < n4) ((f32x4*)p)[i] = (f32x4){0.f, 0.f, 0.f, 0.f};
}

// ---------------- fp32 -> bf16 elementwise (4 per thread) ----------------
__global__ __launch_bounds__(256) void castbf_kernel(const float* __restrict__ src,
                                                     bf16_t* __restrict__ dst) {
    int i = (blockIdx.x * 256 + threadIdx.x) * 4;
    f32x4 v = *(const f32x4*)(src + i);
#pragma unroll
    for (int j = 0; j < 4; j++) dst[i + j] = __float2bfloat16(v[j]);
}

// ---------------- weight transpose + cast: dst[b][c][r] = src[b][r][c] ----------------
// R9: idx enumerates (b, c, r) with r fastest -> coalesced WRITES; strided reads
// are served by L2 (each matrix <= 2.4 MB).
__global__ __launch_bounds__(256) void tcast_kernel(const float* __restrict__ src,
                                                    bf16_t* __restrict__ dst,
                                                    int R, int Cc, int total) {
    int idx = blockIdx.x * 256 + threadIdx.x;
    if (idx >= total) return;
    int rc = R * Cc;
    int b = idx / rc;
    int rem = idx - b * rc;
    int c = rem / R;
    int r = rem - c * R;
    dst[b * rc + c * R + r] = __float2bfloat16(src[b * rc + r * Cc + c]);
}

// ---------------- LayerNorm: one wave per row of 384; input fp32 or bf16 ----------------
template <typename T>
__global__ __launch_bounds__(256) void ln_kernel(const T* __restrict__ x,
                                                 const float* __restrict__ g,
                                                 const float* __restrict__ be,
                                                 bf16_t* __restrict__ out) {
    int wave = threadIdx.x >> 6, lane = threadIdx.x & 63;
    int row = blockIdx.x * 4 + wave;
    const T* xr = x + (size_t)row * CC;
    float v[6];
    float s = 0.f;
#pragma unroll
    for (int i = 0; i < 6; i++) { v[i] = tof(xr[lane + i * 64]); s += v[i]; }
#pragma unroll
    for (int off = 32; off > 0; off >>= 1) s += __shfl_xor(s, off, 64);
    float mean = s * (1.f / 384.f);
    float s2 = 0.f;
#pragma unroll
    for (int i = 0; i < 6; i++) { float d = v[i] - mean; s2 += d * d; }
#pragma unroll
    for (int off = 32; off > 0; off >>= 1) s2 += __shfl_xor(s2, off, 64);
    float rstd = rsqrtf(s2 * (1.f / 384.f) + 1e-5f);
    bf16_t* orow = out + (size_t)row * CC;
#pragma unroll
    for (int i = 0; i < 6; i++) {
        int c = lane + i * 64;
        orow[c] = __float2bfloat16((v[i] - mean) * rstd * g[c] + be[c]);
    }
}

// ---------------- 128x128-tile GEMM, LDS-staged. A: MxK. Bt: NxK. ----------------
// Fragment lane math identical to the verified 64^2 core:
// A-frag [m=r16][k=quad*8+j]; B-frag [n=r16][k=quad*8+j]; D row=quad*4+reg, col=r16.
// EPI: 0 = +bias +fp32 resid -> bf16 (proj->x1b)
//      1 = +bias, relu      -> bf16 (mlp1->f1)
//      2 = +bias +bf16 resid-> fp32 (mlp2->out)
//      3 = qkv scatter (no bias): n-tile 0-2 -> q, 3-5 -> k, 6-8 -> v^T padded
template <int KDIM, int EPI>
__global__ __launch_bounds__(256) void gemm128_kernel(const bf16_t* __restrict__ A,
                                                      const bf16_t* __restrict__ Bt,
                                                      const float* __restrict__ bias,
                                                      const void* __restrict__ resid,
                                                      void* __restrict__ o0,
                                                      void* __restrict__ o1,
                                                      void* __restrict__ o2, int N) {
    const int m0 = blockIdx.x * 128, n0 = blockIdx.y * 128;
    const int tid = threadIdx.x;
    const int lane = tid & 63, wave = tid >> 6;
    const int r16 = lane & 15, quad = lane >> 4;
    const int wm = (wave >> 1) * 64, wn = (wave & 1) * 64;
    __shared__ bf16_t Ash[128][40];   // pad 32->40: bank base (row*20+quad*4)%32, 2-way only
    __shared__ bf16_t Bsh[128][40];
    f32x4 zero = {0.f, 0.f, 0.f, 0.f};
    f32x4 acc[4][4];
#pragma unroll
    for (int i = 0; i < 4; i++)
#pragma unroll
        for (int j = 0; j < 4; j++) acc[i][j] = zero;
    const int srow = tid >> 2;             // 64 rows per 256-thread pass
    const int scol = (tid & 3) * 8;        // 8 elems = 16B per thread
    for (int k0 = 0; k0 < KDIM; k0 += 32) {
        const bf16_t* Ag = A + (size_t)(m0 + srow) * KDIM + k0 + scol;
        const bf16_t* Bg = Bt + (size_t)(n0 + srow) * KDIM + k0 + scol;
        short8 a0 = ld8(Ag);
        short8 a1 = ld8(Ag + (size_t)64 * KDIM);
        short8 b0 = ld8(Bg);
        short8 b1 = ld8(Bg + (size_t)64 * KDIM);
        *(short8*)&Ash[srow][scol]      = a0;
        *(short8*)&Ash[64 + srow][scol] = a1;
        *(short8*)&Bsh[srow][scol]      = b0;
        *(short8*)&Bsh[64 + srow][scol] = b1;
        __syncthreads();
        short8 af[4], bfr[4];
#pragma unroll
        for (int i = 0; i < 4; i++) af[i]  = *(const short8*)&Ash[wm + i * 16 + r16][quad * 8];
#pragma unroll
        for (int i = 0; i < 4; i++) bfr[i] = *(const short8*)&Bsh[wn + i * 16 + r16][quad * 8];
#pragma unroll
        for (int mi = 0; mi < 4; mi++)
#pragma unroll
            for (int ni = 0; ni < 4; ni++)
                acc[mi][ni] = MFMA(af[mi], bfr[ni], acc[mi][ni]);
        __syncthreads();
    }
#pragma unroll
    for (int mi = 0; mi < 4; mi++)
#pragma unroll
        for (int ni = 0; ni < 4; ni++)
#pragma unroll
            for (int reg = 0; reg < 4; reg++) {
                int m = m0 + wm + mi * 16 + quad * 4 + reg;
                int n = n0 + wn + ni * 16 + r16;
                float val = acc[mi][ni][reg];
                if constexpr (EPI == 0) {
                    val += bias[n] + ((const float*)resid)[(size_t)m * N + n];
                    ((bf16_t*)o0)[(size_t)m * N + n] = __float2bfloat16(val);
                } else if constexpr (EPI == 1) {
                    val = fmaxf(val + bias[n], 0.f);
                    ((bf16_t*)o0)[(size_t)m * N + n] = __float2bfloat16(val);
                } else if constexpr (EPI == 2) {
                    val += bias[n] + tof(((const bf16_t*)resid)[(size_t)m * N + n]);
                    ((float*)o0)[(size_t)m * N + n] = val;
                } else {
                    int mat = n / 384;
                    int nr  = n - mat * 384;
                    int head = nr >> 6, d = nr & 63;
                    int b = m >> 11, t = m & 2047;
                    int bh = b * HH + head;
                    bf16_t bv = __float2bfloat16(val);
                    if (mat == 0)      ((bf16_t*)o0)[(size_t)(bh * TT + t) * HS + d] = bv;
                    else if (mat == 1) ((bf16_t*)o1)[(size_t)(bh * TT + t) * HS + d] = bv;
                    else               ((bf16_t*)o2)[(size_t)(bh * HS + d) * VST + t] = bv;
                }
            }
}

// ---------------- colsum partial: block (stile, bh, z); z covers tt in [stile+8z, stile+8z+8) ----------------
__global__ __launch_bounds__(256) void colsum_kernel(const bf16_t* __restrict__ qbf,
                                                     const bf16_t* __restrict__ kbf,
                                                     float* __restrict__ colsum) {
    int stile = blockIdx.x, bh = blockIdx.y, z = blockIdx.z;
    if (stile + z * 8 > 31) return;         // chunk entirely past the end
    int s0 = stile * 64;
    const int lane = threadIdx.x & 63, wave = threadIdx.x >> 6;
    const int r16 = lane & 15, quad = lane >> 4;
    __shared__ float csum[64];
    if (threadIdx.x < 64) csum[threadIdx.x] = 0.f;
    __syncthreads();
    short8 bfr[4][2];
#pragma unroll
    for (int ns = 0; ns < 4; ns++)
#pragma unroll
        for (int kk = 0; kk < 2; kk++)
            bfr[ns][kk] = ld8(kbf + (size_t)(bh * TT + s0 + ns * 16 + r16) * HS + kk * 32 + quad * 8);
    float colacc[4] = {0.f, 0.f, 0.f, 0.f};
    for (int jj = wave; jj < 8; jj += 4) {
        int tt = stile + z * 8 + jj;
        if (tt > 31) break;
#pragma unroll
        for (int ms = 0; ms < 4; ms++) {
            const bf16_t* qp = qbf + (size_t)(bh * TT + tt * 64 + ms * 16 + r16) * HS + quad * 8;
            short8 a0 = ld8(qp);
            short8 a1 = ld8(qp + 32);
#pragma unroll
            for (int ns = 0; ns < 4; ns++) {
                f32x4 sacc = {0.f, 0.f, 0.f, 0.f};
                sacc = MFMA(a0, bfr[ns][0], sacc);
                sacc = MFMA(a1, bfr[ns][1], sacc);
#pragma unroll
                for (int reg = 0; reg < 4; reg++) {
                    int t = tt * 64 + ms * 16 + quad * 4 + reg;
                    int s = s0 + ns * 16 + r16;
                    if (s <= t) colacc[ns] += __expf(sacc[reg] * SCALE);
                }
            }
        }
    }
#pragma unroll
    for (int ns = 0; ns < 4; ns++) atomicAdd(&csum[ns * 16 + r16], colacc[ns]);
    __syncthreads();
    if (threadIdx.x < 64) atomicAdd(&colsum[bh * TT + s0 + threadIdx.x], csum[threadIdx.x]);
}

// ---------------- in-place: vst[bh][d][s] /= colsum[bh][s]  (padded rows) ----------------
__global__ __launch_bounds__(256) void vscale_kernel(bf16_t* __restrict__ vst,
                                                     const float* __restrict__ colsum) {
    int idx = blockIdx.x * 256 + threadIdx.x;   // over 24*64*2048 logical elements
    int s  = idx & (TT - 1);
    int d  = (idx >> 11) & 63;
    int bh = idx >> 17;
    bf16_t* p = vst + (size_t)(bh * HS + d) * VST + s;
    float v = __bfloat162float(*p);
    *p = __float2bfloat16(v / colsum[bh * TT + s]);
}

// ---------------- attention partial: block (ttile, bh, z); z covers st in [8z, min(8z+7, ttile)] ----------------
// R8-proven: K/V tiles LDS-staged once per s-iteration; El wave-private.
__global__ __launch_bounds__(256) void attn_part_kernel(const bf16_t* __restrict__ qbf,
                                                        const bf16_t* __restrict__ kbf,
                                                        const bf16_t* __restrict__ vst,
                                                        float* __restrict__ attnf) {
    int ttile = blockIdx.x, bh = blockIdx.y, z = blockIdx.z;
    int sbeg = z * 8;
    if (sbeg > ttile) return;               // no work for this chunk
    int send = ttile + 1 < sbeg + 8 ? ttile + 1 : sbeg + 8;
    int t0 = ttile * 64;
    const int lane = threadIdx.x & 63, wave = threadIdx.x >> 6;
    const int r16 = lane & 15, quad = lane >> 4;
    __shared__ bf16_t Ksh[64][72];     // K[s-off][d], +8 pad
    __shared__ bf16_t Vsh[64][72];     // V^T[d][s-off], +8 pad
    __shared__ bf16_t El[64][72];      // E[t-off][s-off], wave-private rows
    const int srow = threadIdx.x >> 2;          // staging row (64 rows x 4 threads)
    const int scol = (threadIdx.x & 3) << 4;    // staging col base
    f32x4 zero = {0.f, 0.f, 0.f, 0.f};
    f32x4 oacc[4] = {zero, zero, zero, zero};
    const bf16_t* qp = qbf + (size_t)(bh * TT + t0 + wave * 16 + r16) * HS + quad * 8;
    short8 qa0 = ld8(qp);
    short8 qa1 = ld8(qp + 32);
    for (int st = sbeg; st < send; st++) {
        int s0 = st * 64;
        {
            const bf16_t* kp = kbf + (size_t)(bh * TT + s0 + srow) * HS + scol;
            short8 k0 = ld8(kp);
            short8 k1 = ld8(kp + 8);
            const bf16_t* vp = vst + (size_t)(bh * HS + srow) * VST + s0 + scol;
            short8 v0 = ld8(vp);
            short8 v1 = ld8(vp + 8);
            *(short8*)&Ksh[srow][scol]     = k0;
            *(short8*)&Ksh[srow][scol + 8] = k1;
            *(short8*)&Vsh[srow][scol]     = v0;
            *(short8*)&Vsh[srow][scol + 8] = v1;
        }
        __syncthreads();
#pragma unroll
        for (int ns = 0; ns < 4; ns++) {
            f32x4 sacc = zero;
            sacc = MFMA(qa0, *(const short8*)&Ksh[ns * 16 + r16][quad * 8], sacc);
            sacc = MFMA(qa1, *(const short8*)&Ksh[ns * 16 + r16][32 + quad * 8], sacc);
#pragma unroll
            for (int reg = 0; reg < 4; reg++) {
                int t = t0 + wave * 16 + quad * 4 + reg;
                int s = s0 + ns * 16 + r16;
                float e = (s <= t) ? __expf(sacc[reg] * SCALE) : 0.f;
                El[wave * 16 + quad * 4 + reg][ns * 16 + r16] = __float2bfloat16(e);
            }
        }
#pragma unroll
        for (int ks = 0; ks < 2; ks++) {
            short8 ea = ld8(&El[wave * 16 + r16][ks * 32 + quad * 8]);
#pragma unroll
            for (int ns = 0; ns < 4; ns++) {
                short8 vb = *(const short8*)&Vsh[ns * 16 + r16][ks * 32 + quad * 8];
                oacc[ns] = MFMA(ea, vb, oacc[ns]);
            }
        }
        __syncthreads();   // protect Ksh/Vsh before next staging
    }
    int b = bh / HH, head = bh - b * HH;
#pragma unroll
    for (int ns = 0; ns < 4; ns++)
#pragma unroll
        for (int reg = 0; reg < 4; reg++) {
            int t = t0 + wave * 16 + quad * 4 + reg;
            int d = ns * 16 + r16;
            atomicAdd(&attnf[(size_t)(b * TT + t) * CC + head * HS + d], oacc[ns][reg]);
        }
}

extern "C" void kernel_launch(void* const* d_in, const int* in_sizes, int n_in,
                              void* d_out, int out_size, void* d_ws, size_t ws_size,
                              hipStream_t stream) {
    const float* x      = (const float*)d_in[0];
    const float* wq     = (const float*)d_in[1];
    const float* wk     = (const float*)d_in[2];
    const float* wv     = (const float*)d_in[3];
    const float* w_proj = (const float*)d_in[4];
    const float* b_proj = (const float*)d_in[5];
    const float* w1     = (const float*)d_in[6];
    const float* b1     = (const float*)d_in[7];
    const float* w2     = (const float*)d_in[8];
    const float* b2     = (const float*)d_in[9];
    const float* g1     = (const float*)d_in[10];
    const float* be1    = (const float*)d_in[11];
    const float* g2     = (const float*)d_in[12];
    const float* be2    = (const float*)d_in[13];
    float* out = (float*)d_out;

    // ---- overlaid workspace plan, total 28,803,072 B (proven footprint) ----
    char* p = (char*)d_ws;
    auto alloc = [&](size_t bytes) {
        void* r = (void*)p;
        p += (bytes + 255) & ~(size_t)255;
        return r;
    };
    const size_t ACT  = (size_t)BT * CC * 2;      // 6291456 B
    // wq^T|wk^T|wv^T wall: 3 x 294,912 B, contiguous (each a multiple of 256)
    bf16_t* wqt    = (bf16_t*)alloc(HH * HS * CC * 2);
    bf16_t* wkt    = (bf16_t*)alloc(HH * HS * CC * 2);
    bf16_t* wvt    = (bf16_t*)alloc(HH * HS * CC * 2);
    bf16_t* wpt    = (bf16_t*)alloc(CC * CC * 2);
    bf16_t* w1t    = (bf16_t*)alloc((size_t)C4 * CC * 2);
    bf16_t* w2t    = (bf16_t*)alloc((size_t)CC * C4 * 2);
    // slotA: h (ln1->qkv) -> attn_bf (cast->proj) -> h2 (ln2->mlp1)
    char* slotA = (char*)alloc(ACT);
    // slotB: q|k (qkv->attn) -> f1 chunk 4096x1536 bf16 (mlp)
    char* slotB = (char*)alloc(2 * ACT);
    // slotC: padded v^T (qkv->attn) -> x1b bf16 (proj->end)
    char* slotC = (char*)alloc((size_t)24 * HS * VST * 2);

    bf16_t* h_bf    = (bf16_t*)slotA;
    bf16_t* attn_bf = (bf16_t*)slotA;
    bf16_t* h2_bf   = (bf16_t*)slotA;
    bf16_t* q_bf    = (bf16_t*)slotB;
    bf16_t* k_bf    = (bf16_t*)(slotB + ACT);
    bf16_t* f1      = (bf16_t*)slotB;         // 4096 x 1536 bf16 = 12,582,912 B
    bf16_t* v_bf    = (bf16_t*)slotC;         // [bh][d][VST]
    bf16_t* x1b     = (bf16_t*)slotC;         // bf16 residual stream
    float* colsum   = (float*)wqt;            // overlays wall (dead after qkv)
    float* attn_f   = (float*)d_out;          // fp32 attn accumulator (dead after cast)

    // 0. zero attn accumulator
    zinit_kernel<<<3072, 256, 0, stream>>>(attn_f, BT*CC/4);
    // 1. weight transpose+cast (coalesced writes)
    tcast_kernel<<<(HH*CC*HS + 255)/256, 256, 0, stream>>>(wq, wqt, CC, HS, HH*CC*HS);
    tcast_kernel<<<(HH*CC*HS + 255)/256, 256, 0, stream>>>(wk, wkt, CC, HS, HH*CC*HS);
    tcast_kernel<<<(HH*CC*HS + 255)/256, 256, 0, stream>>>(wv, wvt, CC, HS, HH*CC*HS);
    tcast_kernel<<<(CC*CC + 255)/256, 256, 0, stream>>>(w_proj, wpt, CC, CC, CC*CC);
    tcast_kernel<<<(CC*C4 + 255)/256, 256, 0, stream>>>(w1, w1t, CC, C4, CC*C4);
    tcast_kernel<<<(C4*CC + 255)/256, 256, 0, stream>>>(w2, w2t, C4, CC, C4*CC);
    // 2. LN1
    ln_kernel<float><<<BT/4, 256, 0, stream>>>(x, g1, be1, h_bf);
    // 3. fused QKV: h(8192x384) @ wall^T(1152x384) -> q, k, v^T (128^2 tiles)
    gemm128_kernel<CC, 3><<<dim3(BT/128, 9), 256, 0, stream>>>(
        h_bf, wqt, nullptr, nullptr, q_bf, k_bf, v_bf, 1152);
    // 4. zero colsum (wall dead), column sums of exp(scores)
    zinit_kernel<<<48, 256, 0, stream>>>(colsum, 24*TT/4);
    colsum_kernel<<<dim3(32, 24, 4), 256, 0, stream>>>(q_bf, k_bf, colsum);
    // 5. V /= colsum (in place, padded rows)
    vscale_kernel<<<(24*HS*TT)/256, 256, 0, stream>>>(v_bf, colsum);
    // 6. attention — split over s-chunks, LDS-staged tiles, fp32 atomic accumulate
    attn_part_kernel<<<dim3(32, 24, 4), 256, 0, stream>>>(q_bf, k_bf, v_bf, attn_f);
    // 6b. cast accumulator to bf16 into slotA (h dead)
    castbf_kernel<<<3072, 256, 0, stream>>>(attn_f, attn_bf);
    // 7. proj + bias + resid(x fp32) -> x1b bf16 in slotC (v dead)
    gemm128_kernel<CC, 0><<<dim3(BT/128, CC/128), 256, 0, stream>>>(
        attn_bf, wpt, b_proj, x, x1b, nullptr, nullptr, CC);
    // 8. LN2 (bf16 input) -> h2 in slotA (attn_bf dead)
    ln_kernel<bf16_t><<<BT/4, 256, 0, stream>>>(x1b, g2, be2, h2_bf);
    // 9+10. MLP in 2 row-chunks of 4096 (f1 overlays q|k, dead)
    for (int c = 0; c < 2; c++) {
        size_t m0 = (size_t)c * 4096;
        gemm128_kernel<CC, 1><<<dim3(4096/128, C4/128), 256, 0, stream>>>(
            h2_bf + m0 * CC, w1t, b1, nullptr, f1, nullptr, nullptr, C4);
        gemm128_kernel<C4, 2><<<dim3(4096/128, CC/128), 256, 0, stream>>>(
            f1, w2t, b2, x1b + m0 * CC, out + m0 * CC, nullptr, nullptr, CC);
    }
}

// Round 10
// 361.326 us; speedup vs baseline: 1.6879x; 1.0231x over previous
//
#include <hip/hip_runtime.h>
#include <hip/hip_bf16.h>

// Transformer block: B=4 T=2048 C=384 H=6 HS=64.
// Reference softmax is over the QUERY axis -> w[t,s] = exp(S[t,s])/colsum[s],
// colsum[s] = sum_{t>=s} exp(S[t,s]).  Pipeline: colsum pass, then out = E @ V
// with E pre-divided by colsum (R10: V no longer rescaled in a separate pass).
//
// R10 = R9 (gemm128/attn cores proven) + overhead elimination:
//  - colsum: K-tile LDS-staged once per block (R8-proven pattern).
//  - attn: E scaled by 1/colsum[s] in-kernel -> vscale_kernel deleted; LPT order.
//  - prep_kernel merges the 6 weight tcasts + attn_f zero -> 1 launch.
//  - castbf + bf16 proj kept (fp32-A GEMM path remains unproven from R3/R4).
// Dispatches 19 -> 12. WS total 28,803,072 B (proven footprint).

#define BB 4
#define TT 2048
#define CC 384
#define HH 6
#define HS 64
#define BT 8192
#define C4 1536
#define VST 2080              // padded V^T leading dim (elements): 4160B rows
#define SCALE 0.05103103630798288f   // 384^-0.5

typedef __attribute__((ext_vector_type(8))) short short8;   // 8 x bf16
typedef __attribute__((ext_vector_type(4))) float f32x4;
typedef __hip_bfloat16 bf16_t;

__device__ inline short8 ld8(const bf16_t* p) { return *reinterpret_cast<const short8*>(p); }
__device__ inline float tof(float v) { return v; }
__device__ inline float tof(bf16_t v) { return __bfloat162float(v); }
#define MFMA(a, b, c) __builtin_amdgcn_mfma_f32_16x16x32_bf16(a, b, c, 0, 0, 0)

// ---------------- zero-init ----------------
__global__ __launch_bounds__(256) void zinit_kernel(float* __restrict__ p, int n4) {
    int i = blockIdx.x * 256 + threadIdx.x;
    if (i < n4) ((f32x4*)p)[i] = (f32x4){0.f, 0.f, 0.f, 0.f};
}

// ---------------- fp32 -> bf16 elementwise (4 per thread) ----------------
__global__ __launch_bounds__(256) void castbf_kernel(const float* __restrict__ src,
                                                     bf16_t* __restrict__ dst) {
    int i = (blockIdx.x * 256 + threadIdx.x) * 4;
    f32x4 v = *(const f32x4*)(src + i);
#pragma unroll
    for (int j = 0; j < 4; j++) dst[i + j] = __float2bfloat16(v[j]);
}

// ---------------- prep: all weight transposes + attn_f zero in ONE launch ----------------
__device__ inline void tc(const float* __restrict__ src, bf16_t* __restrict__ dst,
                          int R, int Cc, int idx) {
    int rc = R * Cc;
    int b = idx / rc;
    int rem = idx - b * rc;
    int c = rem / R;
    int r = rem - c * R;
    dst[b * rc + c * R + r] = __float2bfloat16(src[b * rc + r * Cc + c]);
}
#define RW  147456          // wq/wk/wv/wproj element count
#define RW1 589824          // w1/w2 element count
#define NTC (3*RW + RW + 2*RW1)          // 1,769,472 tcast elements
#define NZ  (BT*CC/4)                    // 786,432 f32x4 zeros
__global__ __launch_bounds__(256) void prep_kernel(const float* __restrict__ wq,
                                                   const float* __restrict__ wk,
                                                   const float* __restrict__ wv,
                                                   const float* __restrict__ wproj,
                                                   const float* __restrict__ w1,
                                                   const float* __restrict__ w2,
                                                   bf16_t* __restrict__ wall,   // wqt|wkt|wvt
                                                   bf16_t* __restrict__ wpt,
                                                   bf16_t* __restrict__ w1t,
                                                   bf16_t* __restrict__ w2t,
                                                   float* __restrict__ attnf) {
    int i = blockIdx.x * 256 + threadIdx.x;
    if (i < RW)                tc(wq, wall, CC, HS, i);
    else if (i < 2*RW)         tc(wk, wall + RW, CC, HS, i - RW);
    else if (i < 3*RW)         tc(wv, wall + 2*RW, CC, HS, i - 2*RW);
    else if (i < 4*RW)         tc(wproj, wpt, CC, CC, i - 3*RW);
    else if (i < 4*RW + RW1)   tc(w1, w1t, CC, C4, i - 4*RW);
    else if (i < NTC)          tc(w2, w2t, C4, CC, i - 4*RW - RW1);
    else {
        int z = i - NTC;
        if (z < NZ) ((f32x4*)attnf)[z] = (f32x4){0.f, 0.f, 0.f, 0.f};
    }
}

// ---------------- LayerNorm: one wave per row of 384; input fp32 or bf16 ----------------
template <typename T>
__global__ __launch_bounds__(256) void ln_kernel(const T* __restrict__ x,
                                                 const float* __restrict__ g,
                                                 const float* __restrict__ be,
                                                 bf16_t* __restrict__ out) {
    int wave = threadIdx.x >> 6, lane = threadIdx.x & 63;
    int row = blockIdx.x * 4 + wave;
    const T* xr = x + (size_t)row * CC;
    float v[6];
    float s = 0.f;
#pragma unroll
    for (int i = 0; i < 6; i++) { v[i] = tof(xr[lane + i * 64]); s += v[i]; }
#pragma unroll
    for (int off = 32; off > 0; off >>= 1) s += __shfl_xor(s, off, 64);
    float mean = s * (1.f / 384.f);
    float s2 = 0.f;
#pragma unroll
    for (int i = 0; i < 6; i++) { float d = v[i] - mean; s2 += d * d; }
#pragma unroll
    for (int off = 32; off > 0; off >>= 1) s2 += __shfl_xor(s2, off, 64);
    float rstd = rsqrtf(s2 * (1.f / 384.f) + 1e-5f);
    bf16_t* orow = out + (size_t)row * CC;
#pragma unroll
    for (int i = 0; i < 6; i++) {
        int c = lane + i * 64;
        orow[c] = __float2bfloat16((v[i] - mean) * rstd * g[c] + be[c]);
    }
}

// ---------------- 128x128-tile GEMM, LDS-staged (R9-proven). A: MxK. Bt: NxK. ----------------
template <int KDIM, int EPI>
__global__ __launch_bounds__(256) void gemm128_kernel(const bf16_t* __restrict__ A,
                                                      const bf16_t* __restrict__ Bt,
                                                      const float* __restrict__ bias,
                                                      const void* __restrict__ resid,
                                                      void* __restrict__ o0,
                                                      void* __restrict__ o1,
                                                      void* __restrict__ o2, int N) {
    const int m0 = blockIdx.x * 128, n0 = blockIdx.y * 128;
    const int tid = threadIdx.x;
    const int lane = tid & 63, wave = tid >> 6;
    const int r16 = lane & 15, quad = lane >> 4;
    const int wm = (wave >> 1) * 64, wn = (wave & 1) * 64;
    __shared__ bf16_t Ash[128][40];
    __shared__ bf16_t Bsh[128][40];
    f32x4 zero = {0.f, 0.f, 0.f, 0.f};
    f32x4 acc[4][4];
#pragma unroll
    for (int i = 0; i < 4; i++)
#pragma unroll
        for (int j = 0; j < 4; j++) acc[i][j] = zero;
    const int srow = tid >> 2;
    const int scol = (tid & 3) * 8;
    for (int k0 = 0; k0 < KDIM; k0 += 32) {
        const bf16_t* Ag = A + (size_t)(m0 + srow) * KDIM + k0 + scol;
        const bf16_t* Bg = Bt + (size_t)(n0 + srow) * KDIM + k0 + scol;
        short8 a0 = ld8(Ag);
        short8 a1 = ld8(Ag + (size_t)64 * KDIM);
        short8 b0 = ld8(Bg);
        short8 b1 = ld8(Bg + (size_t)64 * KDIM);
        *(short8*)&Ash[srow][scol]      = a0;
        *(short8*)&Ash[64 + srow][scol] = a1;
        *(short8*)&Bsh[srow][scol]      = b0;
        *(short8*)&Bsh[64 + srow][scol] = b1;
        __syncthreads();
        short8 af[4], bfr[4];
#pragma unroll
        for (int i = 0; i < 4; i++) af[i]  = *(const short8*)&Ash[wm + i * 16 + r16][quad * 8];
#pragma unroll
        for (int i = 0; i < 4; i++) bfr[i] = *(const short8*)&Bsh[wn + i * 16 + r16][quad * 8];
#pragma unroll
        for (int mi = 0; mi < 4; mi++)
#pragma unroll
            for (int ni = 0; ni < 4; ni++)
                acc[mi][ni] = MFMA(af[mi], bfr[ni], acc[mi][ni]);
        __syncthreads();
    }
#pragma unroll
    for (int mi = 0; mi < 4; mi++)
#pragma unroll
        for (int ni = 0; ni < 4; ni++)
#pragma unroll
            for (int reg = 0; reg < 4; reg++) {
                int m = m0 + wm + mi * 16 + quad * 4 + reg;
                int n = n0 + wn + ni * 16 + r16;
                float val = acc[mi][ni][reg];
                if constexpr (EPI == 0) {
                    val += bias[n] + ((const float*)resid)[(size_t)m * N + n];
                    ((bf16_t*)o0)[(size_t)m * N + n] = __float2bfloat16(val);
                } else if constexpr (EPI == 1) {
                    val = fmaxf(val + bias[n], 0.f);
                    ((bf16_t*)o0)[(size_t)m * N + n] = __float2bfloat16(val);
                } else if constexpr (EPI == 2) {
                    val += bias[n] + tof(((const bf16_t*)resid)[(size_t)m * N + n]);
                    ((float*)o0)[(size_t)m * N + n] = val;
                } else {
                    int mat = n / 384;
                    int nr  = n - mat * 384;
                    int head = nr >> 6, d = nr & 63;
                    int b = m >> 11, t = m & 2047;
                    int bh = b * HH + head;
                    bf16_t bv = __float2bfloat16(val);
                    if (mat == 0)      ((bf16_t*)o0)[(size_t)(bh * TT + t) * HS + d] = bv;
                    else if (mat == 1) ((bf16_t*)o1)[(size_t)(bh * TT + t) * HS + d] = bv;
                    else               ((bf16_t*)o2)[(size_t)(bh * HS + d) * VST + t] = bv;
                }
            }
}

// ---------------- colsum partial: block (stile, bh, z); K-tile LDS-staged ----------------
__global__ __launch_bounds__(256) void colsum_kernel(const bf16_t* __restrict__ qbf,
                                                     const bf16_t* __restrict__ kbf,
                                                     float* __restrict__ colsum) {
    int stile = blockIdx.x, bh = blockIdx.y, z = blockIdx.z;
    if (stile + z * 8 > 31) return;
    int s0 = stile * 64;
    const int lane = threadIdx.x & 63, wave = threadIdx.x >> 6;
    const int r16 = lane & 15, quad = lane >> 4;
    __shared__ bf16_t Ksh[64][72];
    __shared__ float csum[64];
    if (threadIdx.x < 64) csum[threadIdx.x] = 0.f;
    {
        const int srow = threadIdx.x >> 2, scol = (threadIdx.x & 3) << 4;
        const bf16_t* kp = kbf + (size_t)(bh * TT + s0 + srow) * HS + scol;
        *(short8*)&Ksh[srow][scol]     = ld8(kp);
        *(short8*)&Ksh[srow][scol + 8] = ld8(kp + 8);
    }
    __syncthreads();
    short8 bfr[4][2];
#pragma unroll
    for (int ns = 0; ns < 4; ns++)
#pragma unroll
        for (int kk = 0; kk < 2; kk++)
            bfr[ns][kk] = *(const short8*)&Ksh[ns * 16 + r16][kk * 32 + quad * 8];
    float colacc[4] = {0.f, 0.f, 0.f, 0.f};
    for (int jj = wave; jj < 8; jj += 4) {
        int tt = stile + z * 8 + jj;
        if (tt > 31) break;
#pragma unroll
        for (int ms = 0; ms < 4; ms++) {
            const bf16_t* qp = qbf + (size_t)(bh * TT + tt * 64 + ms * 16 + r16) * HS + quad * 8;
            short8 a0 = ld8(qp);
            short8 a1 = ld8(qp + 32);
#pragma unroll
            for (int ns = 0; ns < 4; ns++) {
                f32x4 sacc = {0.f, 0.f, 0.f, 0.f};
                sacc = MFMA(a0, bfr[ns][0], sacc);
                sacc = MFMA(a1, bfr[ns][1], sacc);
#pragma unroll
                for (int reg = 0; reg < 4; reg++) {
                    int t = tt * 64 + ms * 16 + quad * 4 + reg;
                    int s = s0 + ns * 16 + r16;
                    if (s <= t) colacc[ns] += __expf(sacc[reg] * SCALE);
                }
            }
        }
    }
#pragma unroll
    for (int ns = 0; ns < 4; ns++) atomicAdd(&csum[ns * 16 + r16], colacc[ns]);
    __syncthreads();
    if (threadIdx.x < 64) atomicAdd(&colsum[bh * TT + s0 + threadIdx.x], csum[threadIdx.x]);
}

// ---------------- attention partial: E/colsum in-kernel, LDS-staged K/V, LPT ----------------
__global__ __launch_bounds__(256) void attn_part_kernel(const bf16_t* __restrict__ qbf,
                                                        const bf16_t* __restrict__ kbf,
                                                        const bf16_t* __restrict__ vst,
                                                        const float* __restrict__ colsum,
                                                        float* __restrict__ attnf) {
    int ttile = 31 - blockIdx.x, bh = blockIdx.y, z = blockIdx.z;   // LPT
    int sbeg = z * 8;
    if (sbeg > ttile) return;
    int send = ttile + 1 < sbeg + 8 ? ttile + 1 : sbeg + 8;
    int t0 = ttile * 64;
    const int lane = threadIdx.x & 63, wave = threadIdx.x >> 6;
    const int r16 = lane & 15, quad = lane >> 4;
    __shared__ bf16_t Ksh[64][72];
    __shared__ bf16_t Vsh[64][72];
    __shared__ bf16_t El[64][72];
    const int srow = threadIdx.x >> 2;
    const int scol = (threadIdx.x & 3) << 4;
    f32x4 zero = {0.f, 0.f, 0.f, 0.f};
    f32x4 oacc[4] = {zero, zero, zero, zero};
    const bf16_t* qp = qbf + (size_t)(bh * TT + t0 + wave * 16 + r16) * HS + quad * 8;
    short8 qa0 = ld8(qp);
    short8 qa1 = ld8(qp + 32);
    for (int st = sbeg; st < send; st++) {
        int s0 = st * 64;
        {
            const bf16_t* kp = kbf + (size_t)(bh * TT + s0 + srow) * HS + scol;
            short8 k0 = ld8(kp);
            short8 k1 = ld8(kp + 8);
            const bf16_t* vp = vst + (size_t)(bh * HS + srow) * VST + s0 + scol;
            short8 v0 = ld8(vp);
            short8 v1 = ld8(vp + 8);
            *(short8*)&Ksh[srow][scol]     = k0;
            *(short8*)&Ksh[srow][scol + 8] = k1;
            *(short8*)&Vsh[srow][scol]     = v0;
            *(short8*)&Vsh[srow][scol + 8] = v1;
        }
        __syncthreads();
#pragma unroll
        for (int ns = 0; ns < 4; ns++) {
            float rc = 1.0f / colsum[bh * TT + s0 + ns * 16 + r16];
            f32x4 sacc = zero;
            sacc = MFMA(qa0, *(const short8*)&Ksh[ns * 16 + r16][quad * 8], sacc);
            sacc = MFMA(qa1, *(const short8*)&Ksh[ns * 16 + r16][32 + quad * 8], sacc);
#pragma unroll
            for (int reg = 0; reg < 4; reg++) {
                int t = t0 + wave * 16 + quad * 4 + reg;
                int s = s0 + ns * 16 + r16;
                float e = (s <= t) ? __expf(sacc[reg] * SCALE) * rc : 0.f;
                El[wave * 16 + quad * 4 + reg][ns * 16 + r16] = __float2bfloat16(e);
            }
        }
#pragma unroll
        for (int ks = 0; ks < 2; ks++) {
            short8 ea = ld8(&El[wave * 16 + r16][ks * 32 + quad * 8]);
#pragma unroll
            for (int ns = 0; ns < 4; ns++) {
                short8 vb = *(const short8*)&Vsh[ns * 16 + r16][ks * 32 + quad * 8];
                oacc[ns] = MFMA(ea, vb, oacc[ns]);
            }
        }
        __syncthreads();
    }
    int b = bh / HH, head = bh - b * HH;
#pragma unroll
    for (int ns = 0; ns < 4; ns++)
#pragma unroll
        for (int reg = 0; reg < 4; reg++) {
            int t = t0 + wave * 16 + quad * 4 + reg;
            int d = ns * 16 + r16;
            atomicAdd(&attnf[(size_t)(b * TT + t) * CC + head * HS + d], oacc[ns][reg]);
        }
}

extern "C" void kernel_launch(void* const* d_in, const int* in_sizes, int n_in,
                              void* d_out, int out_size, void* d_ws, size_t ws_size,
                              hipStream_t stream) {
    const float* x      = (const float*)d_in[0];
    const float* wq     = (const float*)d_in[1];
    const float* wk     = (const float*)d_in[2];
    const float* wv     = (const float*)d_in[3];
    const float* w_proj = (const float*)d_in[4];
    const float* b_proj = (const float*)d_in[5];
    const float* w1     = (const float*)d_in[6];
    const float* b1     = (const float*)d_in[7];
    const float* w2     = (const float*)d_in[8];
    const float* b2     = (const float*)d_in[9];
    const float* g1     = (const float*)d_in[10];
    const float* be1    = (const float*)d_in[11];
    const float* g2     = (const float*)d_in[12];
    const float* be2    = (const float*)d_in[13];
    float* out = (float*)d_out;

    // ---- overlaid workspace plan, total 28,803,072 B (proven footprint) ----
    char* p = (char*)d_ws;
    auto alloc = [&](size_t bytes) {
        void* r = (void*)p;
        p += (bytes + 255) & ~(size_t)255;
        return r;
    };
    const size_t ACT  = (size_t)BT * CC * 2;      // 6291456 B
    bf16_t* wqt    = (bf16_t*)alloc(HH * HS * CC * 2);   // wall base (wq|wk|wv contiguous)
    bf16_t* wkt    = (bf16_t*)alloc(HH * HS * CC * 2);
    bf16_t* wvt    = (bf16_t*)alloc(HH * HS * CC * 2);
    bf16_t* wpt    = (bf16_t*)alloc(CC * CC * 2);
    bf16_t* w1t    = (bf16_t*)alloc((size_t)C4 * CC * 2);
    bf16_t* w2t    = (bf16_t*)alloc((size_t)CC * C4 * 2);
    char* slotA = (char*)alloc(ACT);                       // h -> attn_bf -> h2
    char* slotB = (char*)alloc(2 * ACT);                   // q|k -> f1 chunk
    char* slotC = (char*)alloc((size_t)24 * HS * VST * 2); // v^T padded -> x1b

    bf16_t* h_bf    = (bf16_t*)slotA;
    bf16_t* attn_bf = (bf16_t*)slotA;
    bf16_t* h2_bf   = (bf16_t*)slotA;
    bf16_t* q_bf    = (bf16_t*)slotB;
    bf16_t* k_bf    = (bf16_t*)(slotB + ACT);
    bf16_t* f1      = (bf16_t*)slotB;
    bf16_t* v_bf    = (bf16_t*)slotC;
    bf16_t* x1b     = (bf16_t*)slotC;
    float* colsum   = (float*)wqt;            // overlays wall (dead after qkv)
    float* attn_f   = (float*)d_out;          // fp32 attn accumulator (dead after cast)
    (void)wkt; (void)wvt;

    // 1. prep: all weight tcasts + zero attn_f (one launch)
    prep_kernel<<<(NTC + NZ + 255) / 256, 256, 0, stream>>>(
        wq, wk, wv, w_proj, w1, w2, wqt, wpt, w1t, w2t, attn_f);
    // 2. LN1
    ln_kernel<float><<<BT/4, 256, 0, stream>>>(x, g1, be1, h_bf);
    // 3. fused QKV: h(8192x384) @ wall^T(1152x384) -> q, k, v^T (unscaled)
    gemm128_kernel<CC, 3><<<dim3(BT/128, 9), 256, 0, stream>>>(
        h_bf, wqt, nullptr, nullptr, q_bf, k_bf, v_bf, 1152);
    // 4. zero colsum (wall dead), column sums of exp(scores) — K LDS-staged
    zinit_kernel<<<48, 256, 0, stream>>>(colsum, 24*TT/4);
    colsum_kernel<<<dim3(32, 24, 4), 256, 0, stream>>>(q_bf, k_bf, colsum);
    // 5. attention — E/colsum in-kernel, LDS-staged tiles, fp32 atomic accumulate
    attn_part_kernel<<<dim3(32, 24, 4), 256, 0, stream>>>(q_bf, k_bf, v_bf, colsum, attn_f);
    // 6. cast accumulator to bf16 into slotA (h dead)
    castbf_kernel<<<3072, 256, 0, stream>>>(attn_f, attn_bf);
    // 7. proj + bias + resid(x fp32) -> x1b bf16 in slotC (v dead)
    gemm128_kernel<CC, 0><<<dim3(BT/128, CC/128), 256, 0, stream>>>(
        attn_bf, wpt, b_proj, x, x1b, nullptr, nullptr, CC);
    // 8. LN2 (bf16 input) -> h2 in slotA
    ln_kernel<bf16_t><<<BT/4, 256, 0, stream>>>(x1b, g2, be2, h2_bf);
    // 9+10. MLP in 2 row-chunks of 4096 (f1 overlays q|k, dead)
    for (int c = 0; c < 2; c++) {
        size_t m0 = (size_t)c * 4096;
        gemm128_kernel<CC, 1><<<dim3(4096/128, C4/128), 256, 0, stream>>>(
            h2_bf + m0 * CC, w1t, b1, nullptr, f1, nullptr, nullptr, C4);
        gemm128_kernel<C4, 2><<<dim3(4096/128, CC/128), 256, 0, stream>>>(
            f1, w2t, b2, x1b + m0 * CC, out + m0 * CC, nullptr, nullptr, CC);
    }
}

// Round 11
// 343.414 us; speedup vs baseline: 1.7759x; 1.0522x over previous
//
#include <hip/hip_runtime.h>
#include <hip/hip_bf16.h>

// Transformer block: B=4 T=2048 C=384 H=6 HS=64.
// Reference softmax is over the QUERY axis -> w[t,s] = exp(S[t,s])/colsum[s],
// colsum[s] = sum_{t>=s} exp(S[t,s]).  Pipeline: colsum pass, then out = E @ V
// with E divided by colsum in-kernel.
//
// R11 = R10 with the attn divide fixed: R10 fused 1/colsum as 4 per-lane fp32
// divides + a dependent global load per ns per s-iter (1024 divide chains per
// block-iter) -> attn regressed 60->78us. Now threads 0-63 compute the 64
// reciprocals into LDS (Crc) during the staging phase; the hot loop does a
// broadcast LDS read. LPT reverted (z-split makes it moot; restores R9 geometry).
// Dispatches 12. WS total 28,803,072 B (proven footprint).

#define BB 4
#define TT 2048
#define CC 384
#define HH 6
#define HS 64
#define BT 8192
#define C4 1536
#define VST 2080              // padded V^T leading dim (elements): 4160B rows
#define SCALE 0.05103103630798288f   // 384^-0.5

typedef __attribute__((ext_vector_type(8))) short short8;   // 8 x bf16
typedef __attribute__((ext_vector_type(4))) float f32x4;
typedef __hip_bfloat16 bf16_t;

__device__ inline short8 ld8(const bf16_t* p) { return *reinterpret_cast<const short8*>(p); }
__device__ inline float tof(float v) { return v; }
__device__ inline float tof(bf16_t v) { return __bfloat162float(v); }
#define MFMA(a, b, c) __builtin_amdgcn_mfma_f32_16x16x32_bf16(a, b, c, 0, 0, 0)

// ---------------- zero-init ----------------
__global__ __launch_bounds__(256) void zinit_kernel(float* __restrict__ p, int n4) {
    int i = blockIdx.x * 256 + threadIdx.x;
    if (i < n4) ((f32x4*)p)[i] = (f32x4){0.f, 0.f, 0.f, 0.f};
}

// ---------------- fp32 -> bf16 elementwise (4 per thread) ----------------
__global__ __launch_bounds__(256) void castbf_kernel(const float* __restrict__ src,
                                                     bf16_t* __restrict__ dst) {
    int i = (blockIdx.x * 256 + threadIdx.x) * 4;
    f32x4 v = *(const f32x4*)(src + i);
#pragma unroll
    for (int j = 0; j < 4; j++) dst[i + j] = __float2bfloat16(v[j]);
}

// ---------------- prep: all weight transposes + attn_f zero in ONE launch ----------------
__device__ inline void tc(const float* __restrict__ src, bf16_t* __restrict__ dst,
                          int R, int Cc, int idx) {
    int rc = R * Cc;
    int b = idx / rc;
    int rem = idx - b * rc;
    int c = rem / R;
    int r = rem - c * R;
    dst[b * rc + c * R + r] = __float2bfloat16(src[b * rc + r * Cc + c]);
}
#define RW  147456          // wq/wk/wv/wproj element count
#define RW1 589824          // w1/w2 element count
#define NTC (3*RW + RW + 2*RW1)          // 1,769,472 tcast elements
#define NZ  (BT*CC/4)                    // 786,432 f32x4 zeros
__global__ __launch_bounds__(256) void prep_kernel(const float* __restrict__ wq,
                                                   const float* __restrict__ wk,
                                                   const float* __restrict__ wv,
                                                   const float* __restrict__ wproj,
                                                   const float* __restrict__ w1,
                                                   const float* __restrict__ w2,
                                                   bf16_t* __restrict__ wall,   // wqt|wkt|wvt
                                                   bf16_t* __restrict__ wpt,
                                                   bf16_t* __restrict__ w1t,
                                                   bf16_t* __restrict__ w2t,
                                                   float* __restrict__ attnf) {
    int i = blockIdx.x * 256 + threadIdx.x;
    if (i < RW)                tc(wq, wall, CC, HS, i);
    else if (i < 2*RW)         tc(wk, wall + RW, CC, HS, i - RW);
    else if (i < 3*RW)         tc(wv, wall + 2*RW, CC, HS, i - 2*RW);
    else if (i < 4*RW)         tc(wproj, wpt, CC, CC, i - 3*RW);
    else if (i < 4*RW + RW1)   tc(w1, w1t, CC, C4, i - 4*RW);
    else if (i < NTC)          tc(w2, w2t, C4, CC, i - 4*RW - RW1);
    else {
        int z = i - NTC;
        if (z < NZ) ((f32x4*)attnf)[z] = (f32x4){0.f, 0.f, 0.f, 0.f};
    }
}

// ---------------- LayerNorm: one wave per row of 384; input fp32 or bf16 ----------------
template <typename T>
__global__ __launch_bounds__(256) void ln_kernel(const T* __restrict__ x,
                                                 const float* __restrict__ g,
                                                 const float* __restrict__ be,
                                                 bf16_t* __restrict__ out) {
    int wave = threadIdx.x >> 6, lane = threadIdx.x & 63;
    int row = blockIdx.x * 4 + wave;
    const T* xr = x + (size_t)row * CC;
    float v[6];
    float s = 0.f;
#pragma unroll
    for (int i = 0; i < 6; i++) { v[i] = tof(xr[lane + i * 64]); s += v[i]; }
#pragma unroll
    for (int off = 32; off > 0; off >>= 1) s += __shfl_xor(s, off, 64);
    float mean = s * (1.f / 384.f);
    float s2 = 0.f;
#pragma unroll
    for (int i = 0; i < 6; i++) { float d = v[i] - mean; s2 += d * d; }
#pragma unroll
    for (int off = 32; off > 0; off >>= 1) s2 += __shfl_xor(s2, off, 64);
    float rstd = rsqrtf(s2 * (1.f / 384.f) + 1e-5f);
    bf16_t* orow = out + (size_t)row * CC;
#pragma unroll
    for (int i = 0; i < 6; i++) {
        int c = lane + i * 64;
        orow[c] = __float2bfloat16((v[i] - mean) * rstd * g[c] + be[c]);
    }
}

// ---------------- 128x128-tile GEMM, LDS-staged (R9-proven). A: MxK. Bt: NxK. ----------------
template <int KDIM, int EPI>
__global__ __launch_bounds__(256) void gemm128_kernel(const bf16_t* __restrict__ A,
                                                      const bf16_t* __restrict__ Bt,
                                                      const float* __restrict__ bias,
                                                      const void* __restrict__ resid,
                                                      void* __restrict__ o0,
                                                      void* __restrict__ o1,
                                                      void* __restrict__ o2, int N) {
    const int m0 = blockIdx.x * 128, n0 = blockIdx.y * 128;
    const int tid = threadIdx.x;
    const int lane = tid & 63, wave = tid >> 6;
    const int r16 = lane & 15, quad = lane >> 4;
    const int wm = (wave >> 1) * 64, wn = (wave & 1) * 64;
    __shared__ bf16_t Ash[128][40];
    __shared__ bf16_t Bsh[128][40];
    f32x4 zero = {0.f, 0.f, 0.f, 0.f};
    f32x4 acc[4][4];
#pragma unroll
    for (int i = 0; i < 4; i++)
#pragma unroll
        for (int j = 0; j < 4; j++) acc[i][j] = zero;
    const int srow = tid >> 2;
    const int scol = (tid & 3) * 8;
    for (int k0 = 0; k0 < KDIM; k0 += 32) {
        const bf16_t* Ag = A + (size_t)(m0 + srow) * KDIM + k0 + scol;
        const bf16_t* Bg = Bt + (size_t)(n0 + srow) * KDIM + k0 + scol;
        short8 a0 = ld8(Ag);
        short8 a1 = ld8(Ag + (size_t)64 * KDIM);
        short8 b0 = ld8(Bg);
        short8 b1 = ld8(Bg + (size_t)64 * KDIM);
        *(short8*)&Ash[srow][scol]      = a0;
        *(short8*)&Ash[64 + srow][scol] = a1;
        *(short8*)&Bsh[srow][scol]      = b0;
        *(short8*)&Bsh[64 + srow][scol] = b1;
        __syncthreads();
        short8 af[4], bfr[4];
#pragma unroll
        for (int i = 0; i < 4; i++) af[i]  = *(const short8*)&Ash[wm + i * 16 + r16][quad * 8];
#pragma unroll
        for (int i = 0; i < 4; i++) bfr[i] = *(const short8*)&Bsh[wn + i * 16 + r16][quad * 8];
#pragma unroll
        for (int mi = 0; mi < 4; mi++)
#pragma unroll
            for (int ni = 0; ni < 4; ni++)
                acc[mi][ni] = MFMA(af[mi], bfr[ni], acc[mi][ni]);
        __syncthreads();
    }
#pragma unroll
    for (int mi = 0; mi < 4; mi++)
#pragma unroll
        for (int ni = 0; ni < 4; ni++)
#pragma unroll
            for (int reg = 0; reg < 4; reg++) {
                int m = m0 + wm + mi * 16 + quad * 4 + reg;
                int n = n0 + wn + ni * 16 + r16;
                float val = acc[mi][ni][reg];
                if constexpr (EPI == 0) {
                    val += bias[n] + ((const float*)resid)[(size_t)m * N + n];
                    ((bf16_t*)o0)[(size_t)m * N + n] = __float2bfloat16(val);
                } else if constexpr (EPI == 1) {
                    val = fmaxf(val + bias[n], 0.f);
                    ((bf16_t*)o0)[(size_t)m * N + n] = __float2bfloat16(val);
                } else if constexpr (EPI == 2) {
                    val += bias[n] + tof(((const bf16_t*)resid)[(size_t)m * N + n]);
                    ((float*)o0)[(size_t)m * N + n] = val;
                } else {
                    int mat = n / 384;
                    int nr  = n - mat * 384;
                    int head = nr >> 6, d = nr & 63;
                    int b = m >> 11, t = m & 2047;
                    int bh = b * HH + head;
                    bf16_t bv = __float2bfloat16(val);
                    if (mat == 0)      ((bf16_t*)o0)[(size_t)(bh * TT + t) * HS + d] = bv;
                    else if (mat == 1) ((bf16_t*)o1)[(size_t)(bh * TT + t) * HS + d] = bv;
                    else               ((bf16_t*)o2)[(size_t)(bh * HS + d) * VST + t] = bv;
                }
            }
}

// ---------------- colsum partial: block (stile, bh, z); K-tile LDS-staged (R10-proven) ----------------
__global__ __launch_bounds__(256) void colsum_kernel(const bf16_t* __restrict__ qbf,
                                                     const bf16_t* __restrict__ kbf,
                                                     float* __restrict__ colsum) {
    int stile = blockIdx.x, bh = blockIdx.y, z = blockIdx.z;
    if (stile + z * 8 > 31) return;
    int s0 = stile * 64;
    const int lane = threadIdx.x & 63, wave = threadIdx.x >> 6;
    const int r16 = lane & 15, quad = lane >> 4;
    __shared__ bf16_t Ksh[64][72];
    __shared__ float csum[64];
    if (threadIdx.x < 64) csum[threadIdx.x] = 0.f;
    {
        const int srow = threadIdx.x >> 2, scol = (threadIdx.x & 3) << 4;
        const bf16_t* kp = kbf + (size_t)(bh * TT + s0 + srow) * HS + scol;
        *(short8*)&Ksh[srow][scol]     = ld8(kp);
        *(short8*)&Ksh[srow][scol + 8] = ld8(kp + 8);
    }
    __syncthreads();
    short8 bfr[4][2];
#pragma unroll
    for (int ns = 0; ns < 4; ns++)
#pragma unroll
        for (int kk = 0; kk < 2; kk++)
            bfr[ns][kk] = *(const short8*)&Ksh[ns * 16 + r16][kk * 32 + quad * 8];
    float colacc[4] = {0.f, 0.f, 0.f, 0.f};
    for (int jj = wave; jj < 8; jj += 4) {
        int tt = stile + z * 8 + jj;
        if (tt > 31) break;
#pragma unroll
        for (int ms = 0; ms < 4; ms++) {
            const bf16_t* qp = qbf + (size_t)(bh * TT + tt * 64 + ms * 16 + r16) * HS + quad * 8;
            short8 a0 = ld8(qp);
            short8 a1 = ld8(qp + 32);
#pragma unroll
            for (int ns = 0; ns < 4; ns++) {
                f32x4 sacc = {0.f, 0.f, 0.f, 0.f};
                sacc = MFMA(a0, bfr[ns][0], sacc);
                sacc = MFMA(a1, bfr[ns][1], sacc);
#pragma unroll
                for (int reg = 0; reg < 4; reg++) {
                    int t = tt * 64 + ms * 16 + quad * 4 + reg;
                    int s = s0 + ns * 16 + r16;
                    if (s <= t) colacc[ns] += __expf(sacc[reg] * SCALE);
                }
            }
        }
    }
#pragma unroll
    for (int ns = 0; ns < 4; ns++) atomicAdd(&csum[ns * 16 + r16], colacc[ns]);
    __syncthreads();
    if (threadIdx.x < 64) atomicAdd(&colsum[bh * TT + s0 + threadIdx.x], csum[threadIdx.x]);
}

// ---------------- attention partial: block (ttile, bh, z); LDS-staged K/V + LDS reciprocals ----------------
__global__ __launch_bounds__(256) void attn_part_kernel(const bf16_t* __restrict__ qbf,
                                                        const bf16_t* __restrict__ kbf,
                                                        const bf16_t* __restrict__ vst,
                                                        const float* __restrict__ colsum,
                                                        float* __restrict__ attnf) {
    int ttile = blockIdx.x, bh = blockIdx.y, z = blockIdx.z;
    int sbeg = z * 8;
    if (sbeg > ttile) return;
    int send = ttile + 1 < sbeg + 8 ? ttile + 1 : sbeg + 8;
    int t0 = ttile * 64;
    const int lane = threadIdx.x & 63, wave = threadIdx.x >> 6;
    const int r16 = lane & 15, quad = lane >> 4;
    __shared__ bf16_t Ksh[64][72];
    __shared__ bf16_t Vsh[64][72];
    __shared__ bf16_t El[64][72];
    __shared__ float Crc[64];          // 1/colsum for this s-tile
    const int srow = threadIdx.x >> 2;
    const int scol = (threadIdx.x & 3) << 4;
    f32x4 zero = {0.f, 0.f, 0.f, 0.f};
    f32x4 oacc[4] = {zero, zero, zero, zero};
    const bf16_t* qp = qbf + (size_t)(bh * TT + t0 + wave * 16 + r16) * HS + quad * 8;
    short8 qa0 = ld8(qp);
    short8 qa1 = ld8(qp + 32);
    for (int st = sbeg; st < send; st++) {
        int s0 = st * 64;
        {
            const bf16_t* kp = kbf + (size_t)(bh * TT + s0 + srow) * HS + scol;
            short8 k0 = ld8(kp);
            short8 k1 = ld8(kp + 8);
            const bf16_t* vp = vst + (size_t)(bh * HS + srow) * VST + s0 + scol;
            short8 v0 = ld8(vp);
            short8 v1 = ld8(vp + 8);
            *(short8*)&Ksh[srow][scol]     = k0;
            *(short8*)&Ksh[srow][scol + 8] = k1;
            *(short8*)&Vsh[srow][scol]     = v0;
            *(short8*)&Vsh[srow][scol + 8] = v1;
            if (threadIdx.x < 64)
                Crc[threadIdx.x] = 1.0f / colsum[bh * TT + s0 + threadIdx.x];
        }
        __syncthreads();
#pragma unroll
        for (int ns = 0; ns < 4; ns++) {
            float rc = Crc[ns * 16 + r16];     // broadcast LDS read, conflict-free
            f32x4 sacc = zero;
            sacc = MFMA(qa0, *(const short8*)&Ksh[ns * 16 + r16][quad * 8], sacc);
            sacc = MFMA(qa1, *(const short8*)&Ksh[ns * 16 + r16][32 + quad * 8], sacc);
#pragma unroll
            for (int reg = 0; reg < 4; reg++) {
                int t = t0 + wave * 16 + quad * 4 + reg;
                int s = s0 + ns * 16 + r16;
                float e = (s <= t) ? __expf(sacc[reg] * SCALE) * rc : 0.f;
                El[wave * 16 + quad * 4 + reg][ns * 16 + r16] = __float2bfloat16(e);
            }
        }
#pragma unroll
        for (int ks = 0; ks < 2; ks++) {
            short8 ea = ld8(&El[wave * 16 + r16][ks * 32 + quad * 8]);
#pragma unroll
            for (int ns = 0; ns < 4; ns++) {
                short8 vb = *(const short8*)&Vsh[ns * 16 + r16][ks * 32 + quad * 8];
                oacc[ns] = MFMA(ea, vb, oacc[ns]);
            }
        }
        __syncthreads();
    }
    int b = bh / HH, head = bh - b * HH;
#pragma unroll
    for (int ns = 0; ns < 4; ns++)
#pragma unroll
        for (int reg = 0; reg < 4; reg++) {
            int t = t0 + wave * 16 + quad * 4 + reg;
            int d = ns * 16 + r16;
            atomicAdd(&attnf[(size_t)(b * TT + t) * CC + head * HS + d], oacc[ns][reg]);
        }
}

extern "C" void kernel_launch(void* const* d_in, const int* in_sizes, int n_in,
                              void* d_out, int out_size, void* d_ws, size_t ws_size,
                              hipStream_t stream) {
    const float* x      = (const float*)d_in[0];
    const float* wq     = (const float*)d_in[1];
    const float* wk     = (const float*)d_in[2];
    const float* wv     = (const float*)d_in[3];
    const float* w_proj = (const float*)d_in[4];
    const float* b_proj = (const float*)d_in[5];
    const float* w1     = (const float*)d_in[6];
    const float* b1     = (const float*)d_in[7];
    const float* w2     = (const float*)d_in[8];
    const float* b2     = (const float*)d_in[9];
    const float* g1     = (const float*)d_in[10];
    const float* be1    = (const float*)d_in[11];
    const float* g2     = (const float*)d_in[12];
    const float* be2    = (const float*)d_in[13];
    float* out = (float*)d_out;

    // ---- overlaid workspace plan, total 28,803,072 B (proven footprint) ----
    char* p = (char*)d_ws;
    auto alloc = [&](size_t bytes) {
        void* r = (void*)p;
        p += (bytes + 255) & ~(size_t)255;
        return r;
    };
    const size_t ACT  = (size_t)BT * CC * 2;      // 6291456 B
    bf16_t* wqt    = (bf16_t*)alloc(HH * HS * CC * 2);   // wall base (wq|wk|wv contiguous)
    bf16_t* wkt    = (bf16_t*)alloc(HH * HS * CC * 2);
    bf16_t* wvt    = (bf16_t*)alloc(HH * HS * CC * 2);
    bf16_t* wpt    = (bf16_t*)alloc(CC * CC * 2);
    bf16_t* w1t    = (bf16_t*)alloc((size_t)C4 * CC * 2);
    bf16_t* w2t    = (bf16_t*)alloc((size_t)CC * C4 * 2);
    char* slotA = (char*)alloc(ACT);                       // h -> attn_bf -> h2
    char* slotB = (char*)alloc(2 * ACT);                   // q|k -> f1 chunk
    char* slotC = (char*)alloc((size_t)24 * HS * VST * 2); // v^T padded -> x1b

    bf16_t* h_bf    = (bf16_t*)slotA;
    bf16_t* attn_bf = (bf16_t*)slotA;
    bf16_t* h2_bf   = (bf16_t*)slotA;
    bf16_t* q_bf    = (bf16_t*)slotB;
    bf16_t* k_bf    = (bf16_t*)(slotB + ACT);
    bf16_t* f1      = (bf16_t*)slotB;
    bf16_t* v_bf    = (bf16_t*)slotC;
    bf16_t* x1b     = (bf16_t*)slotC;
    float* colsum   = (float*)wqt;            // overlays wall (dead after qkv)
    float* attn_f   = (float*)d_out;          // fp32 attn accumulator (dead after cast)
    (void)wkt; (void)wvt;

    // 1. prep: all weight tcasts + zero attn_f (one launch)
    prep_kernel<<<(NTC + NZ + 255) / 256, 256, 0, stream>>>(
        wq, wk, wv, w_proj, w1, w2, wqt, wpt, w1t, w2t, attn_f);
    // 2. LN1
    ln_kernel<float><<<BT/4, 256, 0, stream>>>(x, g1, be1, h_bf);
    // 3. fused QKV: h(8192x384) @ wall^T(1152x384) -> q, k, v^T (unscaled)
    gemm128_kernel<CC, 3><<<dim3(BT/128, 9), 256, 0, stream>>>(
        h_bf, wqt, nullptr, nullptr, q_bf, k_bf, v_bf, 1152);
    // 4. zero colsum (wall dead), column sums of exp(scores) — K LDS-staged
    zinit_kernel<<<48, 256, 0, stream>>>(colsum, 24*TT/4);
    colsum_kernel<<<dim3(32, 24, 4), 256, 0, stream>>>(q_bf, k_bf, colsum);
    // 5. attention — LDS-staged K/V + LDS reciprocals, fp32 atomic accumulate
    attn_part_kernel<<<dim3(32, 24, 4), 256, 0, stream>>>(q_bf, k_bf, v_bf, colsum, attn_f);
    // 6. cast accumulator to bf16 into slotA (h dead)
    castbf_kernel<<<3072, 256, 0, stream>>>(attn_f, attn_bf);
    // 7. proj + bias + resid(x fp32) -> x1b bf16 in slotC (v dead)
    gemm128_kernel<CC, 0><<<dim3(BT/128, CC/128), 256, 0, stream>>>(
        attn_bf, wpt, b_proj, x, x1b, nullptr, nullptr, CC);
    // 8. LN2 (bf16 input) -> h2 in slotA
    ln_kernel<bf16_t><<<BT/4, 256, 0, stream>>>(x1b, g2, be2, h2_bf);
    // 9+10. MLP in 2 row-chunks of 4096 (f1 overlays q|k, dead)
    for (int c = 0; c < 2; c++) {
        size_t m0 = (size_t)c * 4096;
        gemm128_kernel<CC, 1><<<dim3(4096/128, C4/128), 256, 0, stream>>>(
            h2_bf + m0 * CC, w1t, b1, nullptr, f1, nullptr, nullptr, C4);
        gemm128_kernel<C4, 2><<<dim3(4096/128, CC/128), 256, 0, stream>>>(
            f1, w2t, b2, x1b + m0 * CC, out + m0 * CC, nullptr, nullptr, CC);
    }
}